// Round 19
// baseline (564.835 us; speedup 1.0000x reference)
//
#include <hip/hip_runtime.h>
#include <hip/hip_bf16.h>
#include <cstdint>
#include <cstddef>

// ---------------- problem constants ----------------
#define HDIM    64
#define WDIM    64
#define LPB     4096            // tokens per batch
#define DMODEL  512
#define DIN     1024
#define CONVD   1088
#define DPROJ   2240            // 2*DIN + 2*32 + 128
#define NHEADS  128
#define NCV     2112            // conv channels total (z 1024 + xBC 1088)

using f16    = _Float16;
using f16x4  = __attribute__((ext_vector_type(4))) _Float16;
using f16x8  = __attribute__((ext_vector_type(8))) _Float16;
using f32x4  = __attribute__((ext_vector_type(4))) float;

__device__ __forceinline__ float siluf(float x) { return x / (1.f + __expf(-x)); }
__device__ __forceinline__ float fsilu(float x) {
  return x * __builtin_amdgcn_rcpf(1.f + __expf(-x));
}

// acc += f16lo(a)*f16lo(b) / hi*hi (f32 accumulate)
__device__ __forceinline__ void fma_mix_lo(float& acc, unsigned a, unsigned b) {
  asm("v_fma_mix_f32 %0, %1, %2, %0 op_sel_hi:[1,1,0]" : "+v"(acc) : "v"(a), "v"(b));
}
__device__ __forceinline__ void fma_mix_hi(float& acc, unsigned a, unsigned b) {
  asm("v_fma_mix_f32 %0, %1, %2, %0 op_sel:[1,1,0] op_sel_hi:[1,1,0]" : "+v"(acc) : "v"(a), "v"(b));
}
__device__ __forceinline__ void fmixl(float& acc, unsigned a, float b) {
  asm("v_fma_mix_f32 %0, %1, %2, %0 op_sel_hi:[1,0,0]" : "+v"(acc) : "v"(a), "v"(b));
}
__device__ __forceinline__ void fmixh(float& acc, unsigned a, float b) {
  asm("v_fma_mix_f32 %0, %1, %2, %0 op_sel:[1,0,0] op_sel_hi:[1,0,0]" : "+v"(acc) : "v"(a), "v"(b));
}
__device__ __forceinline__ void fma8(float* acc, const uint4& v, const uint4& w) {
  fma_mix_lo(acc[0], v.x, w.x);  fma_mix_hi(acc[1], v.x, w.x);
  fma_mix_lo(acc[2], v.y, w.y);  fma_mix_hi(acc[3], v.y, w.y);
  fma_mix_lo(acc[4], v.z, w.z);  fma_mix_hi(acc[5], v.z, w.z);
  fma_mix_lo(acc[6], v.w, w.w);  fma_mix_hi(acc[7], v.w, w.w);
}

// ---------------- f32 -> f16 conversion prep (weights only) ----------------
__global__ __launch_bounds__(256) void k_cvt(const float* __restrict__ in, f16* __restrict__ out) {
  size_t i = ((size_t)blockIdx.x * 256 + threadIdx.x) * 4;
  f32x4 v = *(const f32x4*)(in + i);
  f16x4 o;
  #pragma unroll
  for (int j = 0; j < 4; ++j) o[j] = (f16)v[j];
  *(f16x4*)(out + i) = o;
}

__global__ __launch_bounds__(256) void k_cvt_win(const float* __restrict__ W, f16* __restrict__ out) {
  int i = blockIdx.x * 256 + threadIdx.x;    // over 2304*512
  int row = i >> 9, col = i & 511;
  float v = (row < DPROJ) ? W[row * 512 + col] : 0.f;
  out[i] = (f16)v;
}

// Effective per-channel 3x3 kernels, transposed f16: keffall[tap][channel c<2112].
__global__ __launch_bounds__(256) void k_keff(const float* __restrict__ w33,
                       const float* __restrict__ w13x1, const float* __restrict__ w31x1,
                       const float* __restrict__ w13x2, const float* __restrict__ w31x2,
                       const float* __restrict__ w13bc1, const float* __restrict__ w31bc1,
                       const float* __restrict__ w13bc2, const float* __restrict__ w31bc2,
                       const float* __restrict__ wz,
                       f16* __restrict__ keffall) {
  int j = blockIdx.x * 256 + threadIdx.x;
  if (j >= NCV) return;
  if (j < 1024) {
    #pragma unroll
    for (int tap = 0; tap < 9; ++tap) keffall[tap * NCV + j] = (f16)wz[j * 9 + tap];
    return;
  }
  int jj = j - 1024;
  float kh[3] = {0,0,0}, kw[3] = {0,0,0};
  bool dense = ((jj & 1) == 0);
  if (!dense) {
    int m = jj >> 2;                      // jj = 4m+1 or 4m+3
    if ((jj & 3) == 1) {
      if (m < 256) { for (int t=0;t<3;++t){ kh[t]=w31x1[m*3+t];  kw[t]=w13x1[m*3+t];  } }
      else { int q=m-256; for (int t=0;t<3;++t){ kh[t]=w31bc1[q*3+t]; kw[t]=w13bc1[q*3+t]; } }
    } else {
      if (m < 256) { for (int t=0;t<3;++t){ kh[t]=w31x2[m*3+t];  kw[t]=w13x2[m*3+t];  } }
      else { int q=m-256; for (int t=0;t<3;++t){ kh[t]=w31bc2[q*3+t]; kw[t]=w13bc2[q*3+t]; } }
    }
  }
  #pragma unroll
  for (int dh = 0; dh < 3; ++dh)
    #pragma unroll
    for (int dw = 0; dw < 3; ++dw) {
      float v = dense ? w33[(jj >> 1) * 9 + dh*3 + dw] : kh[dh] * kw[dw];
      keffall[(dh*3 + dw) * NCV + j] = (f16)v;
    }
}

// ==== GEMM1 fused-cvt, XOR-swizzled f32 A-tile ====
// C[M,N] f16 = f16(A_f32[M,K]) @ B_f16[N,K]^T.  m97 128x128 structure.
// A tile: logical [128 rows][8 chunks of 16B]; physical chunk = r*8 + (c ^ (r&7)).
// Staged linearly by global_load_lds with inverse-swizzled GLOBAL source (rule #21).
__global__ __launch_bounds__(256) void k_gemm1c(const float* __restrict__ A,
                                                const f16* __restrict__ Bm, int ldb,
                                                f16* __restrict__ C, int ldc,
                                                int K, int NW, int ntn) {
  __shared__ __align__(16) float As[128 * 32];   // 16 KiB f32 (swizzled)
  __shared__ __align__(16) f16   Bs[128 * 32];   // 8 KiB f16 (linear)

  // bijective chunked XCD swizzle (m204)
  int nwg = gridDim.x, bid = blockIdx.x;
  int q = nwg >> 3, r = nwg & 7;
  int xcd = bid & 7, loc = bid >> 3;
  int wg  = (xcd < r ? xcd * (q + 1) : r * (q + 1) + (xcd - r) * q) + loc;
  long m0 = (long)(wg / ntn) * 128;
  long n0 = (long)(wg % ntn) * 128;

  const int tid  = threadIdx.x;
  const int w    = tid >> 6, lane = tid & 63;
  const int wr   = w >> 1, wc = w & 1;

  f32x4 acc[4][4];
  #pragma unroll
  for (int i = 0; i < 4; ++i)
    #pragma unroll
    for (int j = 0; j < 4; ++j) acc[i][j] = (f32x4){0.f,0.f,0.f,0.f};

  // A staging: thread (i,tid) writes 16B linearly at chunk p=i*256+tid.
  // p -> row r=i*32+(tid>>3), physical in-row chunk tid&7, logical chunk
  // c = (tid&7) ^ (r&7) -> global col = c*4.
  const int arow = tid >> 3;
  const int acolS = ((tid & 7) ^ ((tid >> 3) & 7)) * 4;
  // B staging (m97 linear)
  const int brow = w * 16 + (lane >> 2);
  const int bcol = (lane & 3) * 8;
  const int fr   = lane & 15;
  const int kc   = (lane >> 4) * 8;     // f32/f16 col of fragment
  const int ac0  = 2 * (lane >> 4);     // logical 16B-chunk of A fragment (and +1)

  for (int k0 = 0; k0 < K; k0 += 32) {
    #pragma unroll
    for (int i = 0; i < 4; ++i) {
      __builtin_amdgcn_global_load_lds(
        (const __attribute__((address_space(1))) void*)(A + (m0 + i*32 + arow) * 512L + k0 + acolS),
        (__attribute__((address_space(3))) void*)&As[(i*256 + tid) * 4], 16, 0, 0);
    }
    #pragma unroll
    for (int i = 0; i < 2; ++i) {
      __builtin_amdgcn_global_load_lds(
        (const __attribute__((address_space(1))) void*)(Bm + (n0 + i*64 + brow) * (long)ldb + bcol + k0),
        (__attribute__((address_space(3))) void*)&Bs[(i*4 + w) * 512], 16, 0, 0);
    }
    __syncthreads();
    f16x8 af[4], bf[4];
    #pragma unroll
    for (int f = 0; f < 4; ++f) {
      int rr = wr*64 + f*16 + fr;
      f32x4 a0 = *(const f32x4*)&As[(rr*8 + ( ac0      ^ (rr & 7))) * 4];
      f32x4 a1 = *(const f32x4*)&As[(rr*8 + ((ac0 + 1) ^ (rr & 7))) * 4];
      #pragma unroll
      for (int j = 0; j < 4; ++j) { af[f][j] = (f16)a0[j]; af[f][4+j] = (f16)a1[j]; }
      bf[f] = *(const f16x8*)&Bs[(wc*64 + f*16 + fr) * 32 + kc];
    }
    #pragma unroll
    for (int i = 0; i < 4; ++i)
      #pragma unroll
      for (int j = 0; j < 4; ++j)
        acc[i][j] = __builtin_amdgcn_mfma_f32_16x16x32_f16(af[i], bf[j], acc[i][j], 0, 0, 0);
    __syncthreads();
  }

  const int cr = (lane >> 4) * 4;          // C/D: row=(lane>>4)*4+reg, col=lane&15
  const int cc = lane & 15;
  #pragma unroll
  for (int i = 0; i < 4; ++i) {
    long rbase = m0 + wr*64 + i*16 + cr;
    #pragma unroll
    for (int j = 0; j < 4; ++j) {
      int col = (int)n0 + wc*64 + j*16 + cc;
      if (col < NW) {
        f16* cp = C + rbase * (long)ldc + col;
        #pragma unroll
        for (int r2 = 0; r2 < 4; ++r2) cp[(long)r2 * ldc] = (f16)acc[i][j][r2];
      }
    }
  }
}

// ---- single-pass fp16 MFMA GEMM with optional split-K; m97 structure (GEMM2) ----
template<typename OutT>
__global__ __launch_bounds__(256) void k_gemmf(const f16* __restrict__ A, int lda,
                                               const f16* __restrict__ Bm, int ldb,
                                               OutT* __restrict__ C, int ldc,
                                               int Kseg, int NW, int ntn, int ntmn, long Cseg) {
  __shared__ __align__(16) f16 As[128 * 32];
  __shared__ __align__(16) f16 Bs[128 * 32];

  int nwg = gridDim.x, bid = blockIdx.x;
  int q = nwg >> 3, r = nwg & 7;
  int xcd = bid & 7, loc = bid >> 3;
  int wg  = (xcd < r ? xcd * (q + 1) : r * (q + 1) + (xcd - r) * q) + loc;
  int kseg = wg / ntmn;
  int rem  = wg - kseg * ntmn;
  long m0 = (long)(rem / ntn) * 128;
  long n0 = (long)(rem % ntn) * 128;
  const int kbase = kseg * Kseg;

  const int tid  = threadIdx.x;
  const int w    = tid >> 6, lane = tid & 63;
  const int wr   = w >> 1, wc = w & 1;

  f32x4 acc[4][4];
  #pragma unroll
  for (int i = 0; i < 4; ++i)
    #pragma unroll
    for (int j = 0; j < 4; ++j) acc[i][j] = (f32x4){0.f,0.f,0.f,0.f};

  const int srow = w * 16 + (lane >> 2);
  const int scol = (lane & 3) * 8;
  const long aoff = (m0 + srow) * (long)lda + scol + kbase;
  const long boff = (n0 + srow) * (long)ldb + scol + kbase;
  const int fr = lane & 15;
  const int kc = (lane >> 4) * 8;

  for (int k0 = 0; k0 < Kseg; k0 += 32) {
    #pragma unroll
    for (int i = 0; i < 2; ++i) {
      long ao = aoff + (long)i*64*lda + k0;
      long bo = boff + (long)i*64*ldb + k0;
      int ls = (i*4 + w) * 512;
      __builtin_amdgcn_global_load_lds((const __attribute__((address_space(1))) void*)(A + ao),
                                       (__attribute__((address_space(3))) void*)&As[ls], 16, 0, 0);
      __builtin_amdgcn_global_load_lds((const __attribute__((address_space(1))) void*)(Bm + bo),
                                       (__attribute__((address_space(3))) void*)&Bs[ls], 16, 0, 0);
    }
    __syncthreads();
    f16x8 af[4], bf[4];
    #pragma unroll
    for (int f = 0; f < 4; ++f) {
      af[f] = *(const f16x8*)&As[(wr*64 + f*16 + fr) * 32 + kc];
      bf[f] = *(const f16x8*)&Bs[(wc*64 + f*16 + fr) * 32 + kc];
    }
    #pragma unroll
    for (int i = 0; i < 4; ++i)
      #pragma unroll
      for (int j = 0; j < 4; ++j)
        acc[i][j] = __builtin_amdgcn_mfma_f32_16x16x32_f16(af[i], bf[j], acc[i][j], 0, 0, 0);
    __syncthreads();
  }

  OutT* Cb = C + (long)kseg * Cseg;
  const int cr = (lane >> 4) * 4;
  const int cc = lane & 15;
  #pragma unroll
  for (int i = 0; i < 4; ++i) {
    long rbase = m0 + wr*64 + i*16 + cr;
    #pragma unroll
    for (int j = 0; j < 4; ++j) {
      int col = (int)n0 + wc*64 + j*16 + cc;
      if (col < NW) {
        OutT* cp = Cb + rbase * (long)ldc + col;
        #pragma unroll
        for (int r2 = 0; r2 < 4; ++r2) cp[(long)r2 * ldc] = (OutT)acc[i][j][r2];
      }
    }
  }
}

// ---------------- split-K reduction: out(f32) = sum of 2 f16 partials ----------------
__global__ __launch_bounds__(256) void k_red2h(const f16* __restrict__ part, long seg,
                                               float* __restrict__ out) {
  long i = ((long)blockIdx.x * 256 + threadIdx.x) * 4;
  f16x4 s0 = *(const f16x4*)(part + i);
  f16x4 s1 = *(const f16x4*)(part + seg + i);
  f32x4 o;
  #pragma unroll
  for (int j = 0; j < 4; ++j) o[j] = (float)s0[j] + (float)s1[j];
  *(f32x4*)(out + i) = o;
}

// ------ fused f16 conv: TOKEN-PAIR x dual-chain (r14 form) ------
__global__ __launch_bounds__(192) void k_conv_all(const f16* __restrict__ zx,
                                                  const f16* __restrict__ keffall,
                                                  const float* __restrict__ a2_p,
                                                  const float* __restrict__ dt_bias,
                                                  const float* __restrict__ A_log,
                                                  f16* __restrict__ xbc,
                                                  f16* __restrict__ g2,
                                                  float* __restrict__ dAb) {
  int t = threadIdx.x;
  int bid = blockIdx.x, qq = gridDim.x >> 3;
  int grp = (bid & 7) * qq + (bid >> 3);
  int l0 = grp * 2;
  long lb = (long)(l0 & ~(LPB - 1));
  int h  = (l0 >> 6) & 63;
  int w0 = l0 & 63;

  if (t < 132) {
    int c0 = t * 8;
    int c1 = c0 + 1056;
    float a00[8] = {0,0,0,0,0,0,0,0};
    float a01[8] = {0,0,0,0,0,0,0,0};
    float a10[8] = {0,0,0,0,0,0,0,0};
    float a11[8] = {0,0,0,0,0,0,0,0};
    const uint4 z4 = {0u,0u,0u,0u};

    #pragma unroll
    for (int dh = 0; dh < 3; ++dh) {
      int hh = h + dh - 1;
      if (hh < 0 || hh >= HDIM) continue;
      const f16* rp = zx + (lb + (long)(hh * 64)) * DPROJ;
      uint4 v0[4], v1[4];
      #pragma unroll
      for (int pp = 0; pp < 4; ++pp) {
        int ww = w0 + pp - 1;
        ww = ww < 0 ? 0 : (ww > 63 ? 63 : ww);
        const f16* tp = rp + (long)ww * DPROJ;
        v0[pp] = *(const uint4*)(tp + c0);
        v1[pp] = *(const uint4*)(tp + c1);
      }
      if (w0 == 0)  { v0[0] = z4; v1[0] = z4; }
      if (w0 == 62) { v0[3] = z4; v1[3] = z4; }
      #pragma unroll
      for (int dw = 0; dw < 3; ++dw) {
        uint4 wa = *(const uint4*)&keffall[(dh*3 + dw) * NCV + c0];
        uint4 wb = *(const uint4*)&keffall[(dh*3 + dw) * NCV + c1];
        fma8(a00, v0[dw],     wa);
        fma8(a10, v0[dw + 1], wa);
        fma8(a01, v1[dw],     wb);
        fma8(a11, v1[dw + 1], wb);
      }
    }

    float a2 = a2_p[0];
    #pragma unroll
    for (int ti = 0; ti < 2; ++ti) {
      long l = l0 + ti;
      const float* pc0 = ti ? a10 : a00;
      const float* pc1 = ti ? a11 : a01;
      f16x8 o8;
      if (c0 < 1024) {
        #pragma unroll
        for (int j = 0; j < 8; ++j) o8[j] = (f16)(a2 * fsilu(pc0[j]));
        *(f16x8*)&g2[l * 2048 + 1024 + c0] = o8;
      } else {
        #pragma unroll
        for (int j = 0; j < 8; ++j) o8[j] = (f16)fsilu(pc0[j]);
        *(f16x8*)&xbc[l * (long)CONVD + (c0 - 1024)] = o8;
      }
      f16x8 o9;
      #pragma unroll
      for (int j = 0; j < 8; ++j) o9[j] = (f16)fsilu(pc1[j]);
      *(f16x8*)&xbc[l * (long)CONVD + (c1 - 1024)] = o9;
    }
  } else if (t < 164) {
    int idx = t - 132;
    int ti = idx >> 4;
    int hd = (idx & 15) * 8;
    long l = l0 + ti;
    f16x8 x = *(const f16x8*)&zx[l * (long)DPROJ + NCV + hd];
    f32x4 o0, o1;
    #pragma unroll
    for (int j = 0; j < 8; ++j) {
      float xx = (float)x[j] + dt_bias[hd + j];
      float sp = (xx > 20.f) ? xx : log1pf(__expf(xx));
      float dv = sp * __expf(A_log[hd + j]);
      if (j < 4) o0[j] = dv; else o1[j-4] = dv;
    }
    *(f32x4*)&dAb[l * 128 + hd]     = o0;
    *(f32x4*)&dAb[l * 128 + hd + 4] = o1;
  }
}

// -------- KV partials over 64-token slices, 2-token batched loads --------
__global__ __launch_bounds__(512) void k_kv_part(const f16* __restrict__ xbc,
                                                 const float* __restrict__ dA,
                                                 float* __restrict__ part) {
  int t = threadIdx.x;
  int m = t >> 3, p = t & 7;
  int lc = blockIdx.x, b = blockIdx.y;
  float acc0[16], acc1[16];
  #pragma unroll
  for (int s = 0; s < 16; ++s) { acc0[s] = 0.f; acc1[s] = 0.f; }
  long lbase = (long)b * LPB + lc * 64;
  for (int li = 0; li < 64; li += 2) {
    long row = lbase + li;
    const f16* xr0 = xbc + row * CONVD;
    const f16* xr1 = xr0 + CONVD;
    float2 aa0 = *(const float2*)&dA[row * 128 + 2*m];
    float2 aa1 = *(const float2*)&dA[(row + 1) * 128 + 2*m];
    f16 x00s = xr0[16*m + p],     x01s = xr0[16*m + 8 + p];
    f16 x10s = xr1[16*m + p],     x11s = xr1[16*m + 8 + p];
    uint4 q00 = *(const uint4*)(xr0 + DIN);
    uint4 q01 = *(const uint4*)(xr0 + DIN + 8);
    uint4 q02 = *(const uint4*)(xr0 + DIN + 16);
    uint4 q03 = *(const uint4*)(xr0 + DIN + 24);
    uint4 q10 = *(const uint4*)(xr1 + DIN);
    uint4 q11 = *(const uint4*)(xr1 + DIN + 8);
    uint4 q12 = *(const uint4*)(xr1 + DIN + 16);
    uint4 q13 = *(const uint4*)(xr1 + DIN + 24);
    float xv00 = (float)x00s * aa0.x, xv01 = (float)x01s * aa0.y;
    float xv10 = (float)x10s * aa1.x, xv11 = (float)x11s * aa1.y;
    unsigned a00[4] = {q00.x, q00.y, q00.z, q00.w};
    unsigned a01[4] = {q01.x, q01.y, q01.z, q01.w};
    unsigned a02[4] = {q02.x, q02.y, q02.z, q02.w};
    unsigned a03[4] = {q03.x, q03.y, q03.z, q03.w};
    unsigned a10[4] = {q10.x, q10.y, q10.z, q10.w};
    unsigned a11[4] = {q11.x, q11.y, q11.z, q11.w};
    unsigned a12[4] = {q12.x, q12.y, q12.z, q12.w};
    unsigned a13[4] = {q13.x, q13.y, q13.z, q13.w};
    #pragma unroll
    for (int k = 0; k < 4; ++k) {
      fmixl(acc0[2*k],   a00[k], xv00);  fmixh(acc0[2*k+1],   a00[k], xv00);
      fmixl(acc0[8+2*k], a01[k], xv00);  fmixh(acc0[8+2*k+1], a01[k], xv00);
      fmixl(acc1[2*k],   a02[k], xv01);  fmixh(acc1[2*k+1],   a02[k], xv01);
      fmixl(acc1[8+2*k], a03[k], xv01);  fmixh(acc1[8+2*k+1], a03[k], xv01);
      fmixl(acc0[2*k],   a10[k], xv10);  fmixh(acc0[2*k+1],   a10[k], xv10);
      fmixl(acc0[8+2*k], a11[k], xv10);  fmixh(acc0[8+2*k+1], a11[k], xv10);
      fmixl(acc1[2*k],   a12[k], xv11);  fmixh(acc1[2*k+1],   a12[k], xv11);
      fmixl(acc1[8+2*k], a13[k], xv11);  fmixh(acc1[8+2*k+1], a13[k], xv11);
    }
  }
  long base = ((long)(b*64 + lc)) * 16384 + (long)m * 256;
  #pragma unroll
  for (int s = 0; s < 16; ++s) {
    part[base + s*8 + p]       = acc0[s];
    part[base + 128 + s*8 + p] = acc1[s];
  }
}

// sum 64 partials, vectorized f32x4
__global__ __launch_bounds__(256) void k_kv_red(const float* __restrict__ part,
                                                float* __restrict__ KV) {
  int e4 = (blockIdx.x * 256 + threadIdx.x) * 4;
  int b = blockIdx.y;
  f32x4 s = (f32x4){0.f,0.f,0.f,0.f};
  #pragma unroll 4
  for (int lc = 0; lc < 64; ++lc) {
    f32x4 v = *(const f32x4*)&part[((long)(b*64 + lc)) * 16384 + e4];
    #pragma unroll
    for (int j = 0; j < 4; ++j) s[j] += v[j];
  }
  *(f32x4*)&KV[(long)b * 16384 + e4] = s;
}

// --- y = Q*KV + x*Dp, LayerNorm, scale/shift, *alpha1 -> g2 cols [0,1024) f16 ---
__global__ __launch_bounds__(256) void k_y_ln(const f16* __restrict__ xbc,
                                              const float* __restrict__ KV,
                                              const float* __restrict__ Dp,
                                              const float* __restrict__ ln_g,
                                              const float* __restrict__ ln_b,
                                              const float* __restrict__ sc_p,
                                              const float* __restrict__ sh_p,
                                              const float* __restrict__ a1_p,
                                              f16* __restrict__ g2) {
  __shared__ float Qs[64][32];
  __shared__ float red[2][2][8];
  int t = threadIdx.x;
  int hd = t >> 1, pb = (t & 1) * 4;
  int m = hd >> 1, g = hd & 1;
  int b = blockIdx.x >> 6;
  long l0 = (long)b * LPB + (blockIdx.x & 63) * 64;

  f32x4 kv[16];
  #pragma unroll
  for (int s = 0; s < 16; ++s)
    kv[s] = *(const f32x4*)&KV[(long)b * 16384 + m*256 + g*128 + s*8 + pb];

  {
    int tok = t >> 2, q8 = (t & 3) * 8;
    f16x8 qv = *(const f16x8*)&xbc[(l0 + tok) * CONVD + 1056 + q8];
    #pragma unroll
    for (int j = 0; j < 8; ++j) Qs[tok][q8 + j] = (float)qv[j];
  }
  int c0 = hd*8 + pb;
  f32x4 lg = *(const f32x4*)&ln_g[c0];
  f32x4 lb = *(const f32x4*)&ln_b[c0];
  float dpv = Dp[hd];
  float sc = sc_p[0], sh = sh_p[0], a1 = a1_p[0];
  int wv = t >> 6, lane = t & 63;
  __syncthreads();

  for (int tok = 0; tok < 64; tok += 2) {
    int par = (tok >> 1) & 1;
    long row0 = l0 + tok, row1 = row0 + 1;
    f16x4 xa = *(const f16x4*)&xbc[row0 * CONVD + c0];
    f16x4 xb = *(const f16x4*)&xbc[row1 * CONVD + c0];
    f32x4 ya, yb;
    #pragma unroll
    for (int j = 0; j < 4; ++j) { ya[j] = (float)xa[j] * dpv; yb[j] = (float)xb[j] * dpv; }
    #pragma unroll
    for (int s = 0; s < 16; ++s) {
      float qa = Qs[tok][g*16 + s];
      float qb = Qs[tok + 1][g*16 + s];
      #pragma unroll
      for (int j = 0; j < 4; ++j) {
        ya[j] = fmaf(qa, kv[s][j], ya[j]);
        yb[j] = fmaf(qb, kv[s][j], yb[j]);
      }
    }
    float s1a = ya[0]+ya[1]+ya[2]+ya[3];
    float s2a = ya[0]*ya[0]+ya[1]*ya[1]+ya[2]*ya[2]+ya[3]*ya[3];
    float s1b = yb[0]+yb[1]+yb[2]+yb[3];
    float s2b = yb[0]*yb[0]+yb[1]*yb[1]+yb[2]*yb[2]+yb[3]*yb[3];
    #pragma unroll
    for (int off = 1; off < 64; off <<= 1) {
      s1a += __shfl_xor(s1a, off, 64);
      s2a += __shfl_xor(s2a, off, 64);
      s1b += __shfl_xor(s1b, off, 64);
      s2b += __shfl_xor(s2b, off, 64);
    }
    if (lane == 0) {
      red[par][0][wv*2] = s1a;  red[par][0][wv*2 + 1] = s2a;
      red[par][1][wv*2] = s1b;  red[par][1][wv*2 + 1] = s2b;
    }
    __syncthreads();
    #pragma unroll
    for (int ti = 0; ti < 2; ++ti) {
      const float* rr = red[par][ti];
      float S1 = rr[0] + rr[2] + rr[4] + rr[6];
      float S2 = rr[1] + rr[3] + rr[5] + rr[7];
      float mu   = S1 * (1.f/1024.f);
      float var  = S2 * (1.f/1024.f) - mu*mu;
      float rstd = rsqrtf(var + 1e-5f);
      f32x4& yv = ti ? yb : ya;
      f16x4 o4;
      #pragma unroll
      for (int j = 0; j < 4; ++j) {
        float yn = (yv[j] - mu) * rstd * lg[j] + lb[j];
        o4[j] = (f16)(a1 * (yn * sc + sh));
      }
      *(f16x4*)&g2[(l0 + tok + ti) * 2048 + c0] = o4;
    }
  }
}

// ---------------- host launcher ----------------
extern "C" void kernel_launch(void* const* d_in, const int* in_sizes, int n_in,
                              void* d_out, int out_size, void* d_ws, size_t ws_size,
                              hipStream_t stream) {
  const float* u       = (const float*)d_in[0];
  const float* W_in    = (const float*)d_in[3];
  const float* dt_bias = (const float*)d_in[4];
  const float* A_log   = (const float*)d_in[5];
  const float* Dp      = (const float*)d_in[6];
  const float* w33     = (const float*)d_in[7];
  const float* w13x1   = (const float*)d_in[8];
  const float* w31x1   = (const float*)d_in[9];
  const float* w13x2   = (const float*)d_in[10];
  const float* w31x2   = (const float*)d_in[11];
  const float* w13bc1  = (const float*)d_in[12];
  const float* w31bc1  = (const float*)d_in[13];
  const float* w13bc2  = (const float*)d_in[14];
  const float* w31bc2  = (const float*)d_in[15];
  const float* wz      = (const float*)d_in[16];
  const float* ln_g    = (const float*)d_in[17];
  const float* ln_b    = (const float*)d_in[18];
  const float* sc      = (const float*)d_in[19];
  const float* sh      = (const float*)d_in[20];
  const float* a1      = (const float*)d_in[21];
  const float* a2      = (const float*)d_in[22];
  const float* W_out   = (const float*)d_in[23];

  const size_t B_G2   = 16777216;   // 4096x2048 f16
  const size_t B_ZX   = 18350080;   // 4096x2240 f16
  const size_t B_XBC  = 8912896;    // 4096x1088 f16
  const size_t B_DA   = 2097152;    // 4096x128 f32
  const size_t B_KV   = 65536;      // 16384 f32
  const size_t perC   = B_G2 + B_ZX + B_XBC + B_DA + B_KV;
  const size_t persist = 2359296 + 2097152 + 38912;

  int C = 8;
  while (C > 1 && persist + (size_t)C * perC > ws_size) C >>= 1;
  const int nch = 8 / C;
  const int Mc  = C * LPB;

  char* p = (char*)d_ws;
  f16*   win_f   = (f16*)p;   p += 2359296;   // 2304x512
  f16*   wout_f  = (f16*)p;   p += 2097152;   // 512x2048
  f16*   keffall = (f16*)p;   p += 38912;     // 9x2112 f16 (padded)
  f16*   g2      = (f16*)p;   p += (size_t)C * B_G2;
  f16*   zx      = (f16*)p;   p += (size_t)C * B_ZX;
  f16*   xbc     = (f16*)p;   p += (size_t)C * B_XBC;
  float* dAb     = (float*)p; p += (size_t)C * B_DA;
  float* KV      = (float*)p; p += (size_t)C * B_KV;
  float* part   = (float*)zx;   // kv partials: C*64*16384*4 = C*4.2MB <= C*18.35MB
  f16*   kpart  = (f16*)zx;     // gemm2 split-K f16 partials (after kv_red done)

  k_cvt_win<<<4608, 256, 0, stream>>>(W_in, win_f);
  k_cvt    <<<1024, 256, 0, stream>>>(W_out, wout_f);
  k_keff   <<<9, 256, 0, stream>>>(w33, w13x1, w31x1, w13x2, w31x2,
                                   w13bc1, w31bc1, w13bc2, w31bc2, wz, keffall);

  for (int ch = 0; ch < nch; ++ch) {
    const float* uc   = u + (size_t)ch * Mc * 512;
    float*       outc = (float*)d_out + (size_t)ch * Mc * 512;
    const int ntm = Mc / 128;

    // GEMM1 fused-cvt (swizzled A): zx(f16) = f16(u_f32) @ W_in^T
    k_gemm1c<<<ntm*18, 256, 0, stream>>>(uc, win_f, 512, zx, DPROJ, 512, DPROJ, 18);

    // fused f16 conv (token-pair x dual-chain) + dA
    k_conv_all<<<Mc/2, 192, 0, stream>>>(zx, keffall, a2, dt_bias, A_log,
                                         xbc, g2, dAb);

    // attention KV (64-token slices)
    k_kv_part <<<dim3(64, C), 512, 0, stream>>>(xbc, dAb, part);
    k_kv_red  <<<dim3(16, C), 256, 0, stream>>>(part, KV);
    k_y_ln    <<<C*64, 256, 0, stream>>>(xbc, KV, Dp, ln_g, ln_b, sc, sh, a1, g2);

    // GEMM2: split-K=2 f16 partials in zx arena, then reduce into out
    const long cseg = (long)Mc * 512;
    k_gemmf<f16><<<ntm*4*2, 256, 0, stream>>>(g2, 2048, wout_f, 2048,
                                              kpart, 512, 1024, 512, 4, ntm*4, cseg);
    k_red2h<<<Mc/2, 256, 0, stream>>>(kpart, cseg, outc);
  }
}

// Round 20
// 538.856 us; speedup vs baseline: 1.0482x; 1.0482x over previous
//
#include <hip/hip_runtime.h>
#include <hip/hip_bf16.h>
#include <cstdint>
#include <cstddef>

// ---------------- problem constants ----------------
#define HDIM    64
#define WDIM    64
#define LPB     4096            // tokens per batch
#define DMODEL  512
#define DIN     1024
#define CONVD   1088
#define DPROJ   2240            // 2*DIN + 2*32 + 128
#define NHEADS  128
#define NCV     2112            // conv channels total (z 1024 + xBC 1088)

using f16    = _Float16;
using f16x4  = __attribute__((ext_vector_type(4))) _Float16;
using f16x8  = __attribute__((ext_vector_type(8))) _Float16;
using f32x4  = __attribute__((ext_vector_type(4))) float;

__device__ __forceinline__ float siluf(float x) { return x / (1.f + __expf(-x)); }
// fast silu: rcp instead of IEEE division
__device__ __forceinline__ float fsilu(float x) {
  return x * __builtin_amdgcn_rcpf(1.f + __expf(-x));
}

// acc += f16lo(a) * f16lo(b)  /  acc += f16hi(a) * f16hi(b)   (f32 accumulate)
__device__ __forceinline__ void fma_mix_lo(float& acc, unsigned a, unsigned b) {
  asm("v_fma_mix_f32 %0, %1, %2, %0 op_sel_hi:[1,1,0]" : "+v"(acc) : "v"(a), "v"(b));
}
__device__ __forceinline__ void fma_mix_hi(float& acc, unsigned a, unsigned b) {
  asm("v_fma_mix_f32 %0, %1, %2, %0 op_sel:[1,1,0] op_sel_hi:[1,1,0]" : "+v"(acc) : "v"(a), "v"(b));
}
// acc += f16lo/hi(a) * f32(b)
__device__ __forceinline__ void fmixl(float& acc, unsigned a, float b) {
  asm("v_fma_mix_f32 %0, %1, %2, %0 op_sel_hi:[1,0,0]" : "+v"(acc) : "v"(a), "v"(b));
}
__device__ __forceinline__ void fmixh(float& acc, unsigned a, float b) {
  asm("v_fma_mix_f32 %0, %1, %2, %0 op_sel:[1,0,0] op_sel_hi:[1,0,0]" : "+v"(acc) : "v"(a), "v"(b));
}

// 8-channel fma_mix block: acc[0..7] += v(f16x8) * w(f16x8) in f32
__device__ __forceinline__ void fma8(float* acc, const uint4& v, const uint4& w) {
  fma_mix_lo(acc[0], v.x, w.x);  fma_mix_hi(acc[1], v.x, w.x);
  fma_mix_lo(acc[2], v.y, w.y);  fma_mix_hi(acc[3], v.y, w.y);
  fma_mix_lo(acc[4], v.z, w.z);  fma_mix_hi(acc[5], v.z, w.z);
  fma_mix_lo(acc[6], v.w, w.w);  fma_mix_hi(acc[7], v.w, w.w);
}

// ---------------- f32 -> f16 conversion preps ----------------
__global__ __launch_bounds__(256) void k_cvt(const float* __restrict__ in, f16* __restrict__ out) {
  size_t i = ((size_t)blockIdx.x * 256 + threadIdx.x) * 4;
  f32x4 v = *(const f32x4*)(in + i);
  f16x4 o;
  #pragma unroll
  for (int j = 0; j < 4; ++j) o[j] = (f16)v[j];
  *(f16x4*)(out + i) = o;
}

// W_in with zero-pad to 2304 rows
__global__ __launch_bounds__(256) void k_cvt_win(const float* __restrict__ W, f16* __restrict__ out) {
  int i = blockIdx.x * 256 + threadIdx.x;    // over 2304*512
  int row = i >> 9, col = i & 511;
  float v = (row < DPROJ) ? W[row * 512 + col] : 0.f;
  out[i] = (f16)v;
}

// Effective per-channel 3x3 kernels, transposed f16: keffall[tap][channel c<2112].
__global__ __launch_bounds__(256) void k_keff(const float* __restrict__ w33,
                       const float* __restrict__ w13x1, const float* __restrict__ w31x1,
                       const float* __restrict__ w13x2, const float* __restrict__ w31x2,
                       const float* __restrict__ w13bc1, const float* __restrict__ w31bc1,
                       const float* __restrict__ w13bc2, const float* __restrict__ w31bc2,
                       const float* __restrict__ wz,
                       f16* __restrict__ keffall) {
  int j = blockIdx.x * 256 + threadIdx.x;
  if (j >= NCV) return;
  if (j < 1024) {
    #pragma unroll
    for (int tap = 0; tap < 9; ++tap) keffall[tap * NCV + j] = (f16)wz[j * 9 + tap];
    return;
  }
  int jj = j - 1024;
  float kh[3] = {0,0,0}, kw[3] = {0,0,0};
  bool dense = ((jj & 1) == 0);
  if (!dense) {
    int m = jj >> 2;                      // jj = 4m+1 or 4m+3
    if ((jj & 3) == 1) {
      if (m < 256) { for (int t=0;t<3;++t){ kh[t]=w31x1[m*3+t];  kw[t]=w13x1[m*3+t];  } }
      else { int q=m-256; for (int t=0;t<3;++t){ kh[t]=w31bc1[q*3+t]; kw[t]=w13bc1[q*3+t]; } }
    } else {
      if (m < 256) { for (int t=0;t<3;++t){ kh[t]=w31x2[m*3+t];  kw[t]=w13x2[m*3+t];  } }
      else { int q=m-256; for (int t=0;t<3;++t){ kh[t]=w31bc2[q*3+t]; kw[t]=w13bc2[q*3+t]; } }
    }
  }
  #pragma unroll
  for (int dh = 0; dh < 3; ++dh)
    #pragma unroll
    for (int dw = 0; dw < 3; ++dw) {
      float v = dense ? w33[(jj >> 1) * 9 + dh*3 + dw] : kh[dh] * kw[dw];
      keffall[(dh*3 + dw) * NCV + j] = (f16)v;
    }
}

// ---- single-pass fp16 MFMA GEMM with optional split-K; m97 structure, 128x128 tile ----
template<typename OutT>
__global__ __launch_bounds__(256) void k_gemmf(const f16* __restrict__ A, int lda,
                                               const f16* __restrict__ Bm, int ldb,
                                               OutT* __restrict__ C, int ldc,
                                               int Kseg, int NW, int ntn, int ntmn, long Cseg) {
  __shared__ __align__(16) f16 As[128 * 32];
  __shared__ __align__(16) f16 Bs[128 * 32];

  // bijective chunked XCD swizzle (m204)
  int nwg = gridDim.x, bid = blockIdx.x;
  int q = nwg >> 3, r = nwg & 7;
  int xcd = bid & 7, loc = bid >> 3;
  int wg  = (xcd < r ? xcd * (q + 1) : r * (q + 1) + (xcd - r) * q) + loc;
  int kseg = wg / ntmn;
  int rem  = wg - kseg * ntmn;
  long m0 = (long)(rem / ntn) * 128;
  long n0 = (long)(rem % ntn) * 128;
  const int kbase = kseg * Kseg;

  const int tid  = threadIdx.x;
  const int w    = tid >> 6, lane = tid & 63;
  const int wr   = w >> 1, wc = w & 1;

  f32x4 acc[4][4];
  #pragma unroll
  for (int i = 0; i < 4; ++i)
    #pragma unroll
    for (int j = 0; j < 4; ++j) acc[i][j] = (f32x4){0.f,0.f,0.f,0.f};

  const int srow = w * 16 + (lane >> 2);   // staging row within 64-row half
  const int scol = (lane & 3) * 8;         // 8 f16 = 16B per lane
  const long aoff = (m0 + srow) * (long)lda + scol + kbase;
  const long boff = (n0 + srow) * (long)ldb + scol + kbase;
  const int fr = lane & 15;
  const int kc = (lane >> 4) * 8;

  for (int k0 = 0; k0 < Kseg; k0 += 32) {
    #pragma unroll
    for (int i = 0; i < 2; ++i) {
      long ao = aoff + (long)i*64*lda + k0;
      long bo = boff + (long)i*64*ldb + k0;
      int ls = (i*4 + w) * 512;
      __builtin_amdgcn_global_load_lds((const __attribute__((address_space(1))) void*)(A + ao),
                                       (__attribute__((address_space(3))) void*)&As[ls], 16, 0, 0);
      __builtin_amdgcn_global_load_lds((const __attribute__((address_space(1))) void*)(Bm + bo),
                                       (__attribute__((address_space(3))) void*)&Bs[ls], 16, 0, 0);
    }
    __syncthreads();
    f16x8 af[4], bf[4];
    #pragma unroll
    for (int f = 0; f < 4; ++f) {
      af[f] = *(const f16x8*)&As[(wr*64 + f*16 + fr) * 32 + kc];
      bf[f] = *(const f16x8*)&Bs[(wc*64 + f*16 + fr) * 32 + kc];
    }
    #pragma unroll
    for (int i = 0; i < 4; ++i)
      #pragma unroll
      for (int j = 0; j < 4; ++j)
        acc[i][j] = __builtin_amdgcn_mfma_f32_16x16x32_f16(af[i], bf[j], acc[i][j], 0, 0, 0);
    __syncthreads();
  }

  OutT* Cb = C + (long)kseg * Cseg;
  const int cr = (lane >> 4) * 4;          // C/D: row=(lane>>4)*4+reg, col=lane&15
  const int cc = lane & 15;
  #pragma unroll
  for (int i = 0; i < 4; ++i) {
    long rbase = m0 + wr*64 + i*16 + cr;
    #pragma unroll
    for (int j = 0; j < 4; ++j) {
      int col = (int)n0 + wc*64 + j*16 + cc;
      if (col < NW) {
        OutT* cp = Cb + rbase * (long)ldc + col;
        #pragma unroll
        for (int r2 = 0; r2 < 4; ++r2) cp[(long)r2 * ldc] = (OutT)acc[i][j][r2];
      }
    }
  }
}

// ---------------- split-K reduction: out(f32) = sum of 2 f16 partials ----------------
__global__ __launch_bounds__(256) void k_red2h(const f16* __restrict__ part, long seg,
                                               float* __restrict__ out) {
  long i = ((long)blockIdx.x * 256 + threadIdx.x) * 4;
  f16x4 s0 = *(const f16x4*)(part + i);
  f16x4 s1 = *(const f16x4*)(part + seg + i);
  f32x4 o;
  #pragma unroll
  for (int j = 0; j < 4; ++j) o[j] = (float)s0[j] + (float)s1[j];
  *(f32x4*)(out + i) = o;
}

// ------ fused f16 conv: TOKEN-PAIR x dual-chain. Block = 2 adjacent w-tokens. ------
// 192 threads: t<132 conv (16ch x 2 tokens), t in [132,164) dA (8 heads x token).
__global__ __launch_bounds__(192) void k_conv_all(const f16* __restrict__ zx,
                                                  const f16* __restrict__ keffall,
                                                  const float* __restrict__ a2_p,
                                                  const float* __restrict__ dt_bias,
                                                  const float* __restrict__ A_log,
                                                  f16* __restrict__ xbc,
                                                  f16* __restrict__ g2,
                                                  float* __restrict__ dAb) {
  int t = threadIdx.x;
  // XCD-chunk swizzle over token pairs (gridDim.x % 8 == 0)
  int bid = blockIdx.x, qq = gridDim.x >> 3;
  int grp = (bid & 7) * qq + (bid >> 3);
  int l0 = grp * 2;                          // even token; pair shares image row
  long lb = (long)(l0 & ~(LPB - 1));         // batch base row
  int h  = (l0 >> 6) & 63;
  int w0 = l0 & 63;                          // even, 0..62

  if (t < 132) {
    int c0 = t * 8;                          // [0,1056)
    int c1 = c0 + 1056;                      // [1056,2112)
    float a00[8] = {0,0,0,0,0,0,0,0};        // token0 chain0
    float a01[8] = {0,0,0,0,0,0,0,0};        // token0 chain1
    float a10[8] = {0,0,0,0,0,0,0,0};        // token1 chain0
    float a11[8] = {0,0,0,0,0,0,0,0};        // token1 chain1
    const uint4 z4 = {0u,0u,0u,0u};

    #pragma unroll
    for (int dh = 0; dh < 3; ++dh) {
      int hh = h + dh - 1;
      if (hh < 0 || hh >= HDIM) continue;    // block-uniform
      const f16* rp = zx + (lb + (long)(hh * 64)) * DPROJ;
      uint4 v0[4], v1[4];
      #pragma unroll
      for (int pp = 0; pp < 4; ++pp) {       // positions w0-1 .. w0+2
        int ww = w0 + pp - 1;
        ww = ww < 0 ? 0 : (ww > 63 ? 63 : ww);
        const f16* tp = rp + (long)ww * DPROJ;
        v0[pp] = *(const uint4*)(tp + c0);
        v1[pp] = *(const uint4*)(tp + c1);
      }
      if (w0 == 0)  { v0[0] = z4; v1[0] = z4; }   // block-uniform edge zeroing
      if (w0 == 62) { v0[3] = z4; v1[3] = z4; }
      #pragma unroll
      for (int dw = 0; dw < 3; ++dw) {
        uint4 wa = *(const uint4*)&keffall[(dh*3 + dw) * NCV + c0];
        uint4 wb = *(const uint4*)&keffall[(dh*3 + dw) * NCV + c1];
        fma8(a00, v0[dw],     wa);           // token0 uses positions dw
        fma8(a10, v0[dw + 1], wa);           // token1 uses positions dw+1
        fma8(a01, v1[dw],     wb);
        fma8(a11, v1[dw + 1], wb);
      }
    }

    float a2 = a2_p[0];
    #pragma unroll
    for (int ti = 0; ti < 2; ++ti) {
      long l = l0 + ti;
      const float* pc0 = ti ? a10 : a00;
      const float* pc1 = ti ? a11 : a01;
      f16x8 o8;
      if (c0 < 1024) {                       // chain0 -> z region
        #pragma unroll
        for (int j = 0; j < 8; ++j) o8[j] = (f16)(a2 * fsilu(pc0[j]));
        *(f16x8*)&g2[l * 2048 + 1024 + c0] = o8;
      } else {                               // chain0 tail -> xbc
        #pragma unroll
        for (int j = 0; j < 8; ++j) o8[j] = (f16)fsilu(pc0[j]);
        *(f16x8*)&xbc[l * (long)CONVD + (c0 - 1024)] = o8;
      }
      f16x8 o9;
      #pragma unroll
      for (int j = 0; j < 8; ++j) o9[j] = (f16)fsilu(pc1[j]);
      *(f16x8*)&xbc[l * (long)CONVD + (c1 - 1024)] = o9;
    }
  } else if (t < 164) {                      // dA: 32 threads = 2 tokens x 16 x 8 heads
    int idx = t - 132;
    int ti = idx >> 4;
    int hd = (idx & 15) * 8;
    long l = l0 + ti;
    f16x8 x = *(const f16x8*)&zx[l * (long)DPROJ + NCV + hd];
    f32x4 o0, o1;
    #pragma unroll
    for (int j = 0; j < 8; ++j) {
      float xx = (float)x[j] + dt_bias[hd + j];
      float sp = (xx > 20.f) ? xx : log1pf(__expf(xx));
      float dv = sp * __expf(A_log[hd + j]);
      if (j < 4) o0[j] = dv; else o1[j-4] = dv;
    }
    *(f32x4*)&dAb[l * 128 + hd]     = o0;
    *(f32x4*)&dAb[l * 128 + hd + 4] = o1;
  }
}

// ---------------- KV partials over 32-token slices (vectorized B loads) ----------------
__global__ __launch_bounds__(512) void k_kv_part(const f16* __restrict__ xbc,
                                                 const float* __restrict__ dA,
                                                 float* __restrict__ part) {
  int t = threadIdx.x;
  int m = t >> 3, p = t & 7;                 // m: head-pair 0..63, p: headdim 0..7
  int lc = blockIdx.x, b = blockIdx.y;       // lc: 0..127 (32 tokens each), b chunk-local
  float acc0[16], acc1[16];
  #pragma unroll
  for (int s = 0; s < 16; ++s) { acc0[s] = 0.f; acc1[s] = 0.f; }
  long lbase = (long)b * LPB + lc * 32;
  #pragma unroll 2
  for (int li = 0; li < 32; ++li) {
    long row = lbase + li;
    const f16* xr = xbc + row * CONVD;
    float2 aa = *(const float2*)&dA[row * 128 + 2*m];        // dA heads 2m, 2m+1
    float xv0 = (float)xr[16*m + p]     * aa.x;              // head 2m   (group 0)
    float xv1 = (float)xr[16*m + 8 + p] * aa.y;              // head 2m+1 (group 1)
    uint4 q0 = *(const uint4*)(xr + DIN);                    // B g0 s0..7
    uint4 q1 = *(const uint4*)(xr + DIN + 8);                // B g0 s8..15
    uint4 q2 = *(const uint4*)(xr + DIN + 16);               // B g1 s0..7
    uint4 q3 = *(const uint4*)(xr + DIN + 24);               // B g1 s8..15
    unsigned a0[4] = {q0.x, q0.y, q0.z, q0.w};
    unsigned a1[4] = {q1.x, q1.y, q1.z, q1.w};
    unsigned a2v[4] = {q2.x, q2.y, q2.z, q2.w};
    unsigned a3[4] = {q3.x, q3.y, q3.z, q3.w};
    #pragma unroll
    for (int k = 0; k < 4; ++k) {
      fmixl(acc0[2*k],     a0[k], xv0);  fmixh(acc0[2*k+1],     a0[k], xv0);
      fmixl(acc0[8+2*k],   a1[k], xv0);  fmixh(acc0[8+2*k+1],   a1[k], xv0);
      fmixl(acc1[2*k],     a2v[k], xv1); fmixh(acc1[2*k+1],     a2v[k], xv1);
      fmixl(acc1[8+2*k],   a3[k], xv1);  fmixh(acc1[8+2*k+1],   a3[k], xv1);
    }
  }
  long base = ((long)(b*128 + lc)) * 16384 + (long)m * 256;
  #pragma unroll
  for (int s = 0; s < 16; ++s) {
    part[base + s*8 + p]       = acc0[s];
    part[base + 128 + s*8 + p] = acc1[s];
  }
}

__global__ __launch_bounds__(256) void k_kv_red(const float* __restrict__ part,
                                                float* __restrict__ KV) {
  int e = blockIdx.x * 256 + threadIdx.x;   // 16384 per b
  int b = blockIdx.y;
  float s = 0.f;
  #pragma unroll 4
  for (int lc = 0; lc < 128; ++lc) s += part[((long)(b*128 + lc)) * 16384 + e];
  KV[(long)b * 16384 + e] = s;
}

// --- y = Q*KV + x*Dp, LayerNorm, scale/shift, *alpha1 -> g2 cols [0,1024) f16 ---
__global__ __launch_bounds__(256) void k_y_ln(const f16* __restrict__ xbc,
                                              const float* __restrict__ KV,
                                              const float* __restrict__ Dp,
                                              const float* __restrict__ ln_g,
                                              const float* __restrict__ ln_b,
                                              const float* __restrict__ sc_p,
                                              const float* __restrict__ sh_p,
                                              const float* __restrict__ a1_p,
                                              f16* __restrict__ g2) {
  __shared__ float Qs[32][32];
  __shared__ float red[2][8];
  int t = threadIdx.x;
  int hd = t >> 1, pb = (t & 1) * 4;
  int m = hd >> 1, g = hd & 1;
  int b = blockIdx.x >> 7;                  // chunk-local batch (128 groups/batch)
  long l0 = (long)b * LPB + (blockIdx.x & 127) * 32;

  f32x4 kv[16];
  #pragma unroll
  for (int s = 0; s < 16; ++s)
    kv[s] = *(const f32x4*)&KV[(long)b * 16384 + m*256 + g*128 + s*8 + pb];

  if (t < 128) {                            // vectorized Q staging: 128 x f16x8
    int tok = t >> 2, q8 = (t & 3) * 8;
    f16x8 qv = *(const f16x8*)&xbc[(l0 + tok) * CONVD + 1056 + q8];
    #pragma unroll
    for (int j = 0; j < 8; ++j) Qs[tok][q8 + j] = (float)qv[j];
  }
  int c0 = hd*8 + pb;
  f32x4 lg = *(const f32x4*)&ln_g[c0];
  f32x4 lb = *(const f32x4*)&ln_b[c0];
  float dpv = Dp[hd];
  float sc = sc_p[0], sh = sh_p[0], a1 = a1_p[0];
  int wv = t >> 6, lane = t & 63;
  __syncthreads();

  for (int tok = 0; tok < 32; ++tok) {
    long row = l0 + tok;
    f16x4 xr4 = *(const f16x4*)&xbc[row * CONVD + c0];
    f32x4 yv;
    #pragma unroll
    for (int j = 0; j < 4; ++j) yv[j] = (float)xr4[j] * dpv;
    #pragma unroll
    for (int s = 0; s < 16; ++s) {
      float qv = Qs[tok][g*16 + s];
      #pragma unroll
      for (int j = 0; j < 4; ++j) yv[j] = fmaf(qv, kv[s][j], yv[j]);
    }
    float s1 = yv[0] + yv[1] + yv[2] + yv[3];
    float s2 = yv[0]*yv[0] + yv[1]*yv[1] + yv[2]*yv[2] + yv[3]*yv[3];
    #pragma unroll
    for (int off = 1; off < 64; off <<= 1) {
      s1 += __shfl_xor(s1, off, 64);
      s2 += __shfl_xor(s2, off, 64);
    }
    if (lane == 0) { red[tok & 1][wv*2] = s1; red[tok & 1][wv*2 + 1] = s2; }
    __syncthreads();                        // single barrier (parity buffer)
    const float* rr = red[tok & 1];
    float S1 = rr[0] + rr[2] + rr[4] + rr[6];
    float S2 = rr[1] + rr[3] + rr[5] + rr[7];
    float mu   = S1 * (1.f/1024.f);
    float var  = S2 * (1.f/1024.f) - mu*mu;
    float rstd = rsqrtf(var + 1e-5f);
    f16x4 o4;
    #pragma unroll
    for (int j = 0; j < 4; ++j) {
      float yn = (yv[j] - mu) * rstd * lg[j] + lb[j];
      o4[j] = (f16)(a1 * (yn * sc + sh));
    }
    *(f16x4*)&g2[row * 2048 + c0] = o4;
  }
}

// ---------------- host launcher ----------------
extern "C" void kernel_launch(void* const* d_in, const int* in_sizes, int n_in,
                              void* d_out, int out_size, void* d_ws, size_t ws_size,
                              hipStream_t stream) {
  const float* u       = (const float*)d_in[0];
  const float* W_in    = (const float*)d_in[3];
  const float* dt_bias = (const float*)d_in[4];
  const float* A_log   = (const float*)d_in[5];
  const float* Dp      = (const float*)d_in[6];
  const float* w33     = (const float*)d_in[7];
  const float* w13x1   = (const float*)d_in[8];
  const float* w31x1   = (const float*)d_in[9];
  const float* w13x2   = (const float*)d_in[10];
  const float* w31x2   = (const float*)d_in[11];
  const float* w13bc1  = (const float*)d_in[12];
  const float* w31bc1  = (const float*)d_in[13];
  const float* w13bc2  = (const float*)d_in[14];
  const float* w31bc2  = (const float*)d_in[15];
  const float* wz      = (const float*)d_in[16];
  const float* ln_g    = (const float*)d_in[17];
  const float* ln_b    = (const float*)d_in[18];
  const float* sc      = (const float*)d_in[19];
  const float* sh      = (const float*)d_in[20];
  const float* a1      = (const float*)d_in[21];
  const float* a2      = (const float*)d_in[22];
  const float* W_out   = (const float*)d_in[23];

  // per-batch buffer bytes (u_f16 aliases g2; kv partials + gemm2 partials live in zx)
  const size_t B_G2   = 16777216;   // 4096x2048 f16
  const size_t B_ZX   = 18350080;   // 4096x2240 f16
  const size_t B_XBC  = 8912896;    // 4096x1088 f16
  const size_t B_DA   = 2097152;    // 4096x128 f32
  const size_t B_KV   = 65536;      // 16384 f32
  const size_t perC   = B_G2 + B_ZX + B_XBC + B_DA + B_KV;   // 46.2 MB
  const size_t persist = 2359296 + 2097152 + 38912;

  int C = 8;
  while (C > 1 && persist + (size_t)C * perC > ws_size) C >>= 1;
  const int nch = 8 / C;
  const int Mc  = C * LPB;

  char* p = (char*)d_ws;
  f16*   win_f   = (f16*)p;   p += 2359296;   // 2304x512
  f16*   wout_f  = (f16*)p;   p += 2097152;   // 512x2048
  f16*   keffall = (f16*)p;   p += 38912;     // 9x2112 f16 (padded)
  char*  arena   = p;                          // u_f16 aliases g2 (conv rewrites it later)
  f16*   g2      = (f16*)arena;
  f16*   u_f     = (f16*)arena;
  p = arena + (size_t)C * B_G2;
  f16*   zx      = (f16*)p;   p += (size_t)C * B_ZX;
  f16*   xbc     = (f16*)p;   p += (size_t)C * B_XBC;
  float* dAb     = (float*)p; p += (size_t)C * B_DA;
  float* KV      = (float*)p; p += (size_t)C * B_KV;
  float* part   = (float*)zx;                 // kv partials (after conv, zx dead)
  f16*   kpart  = (f16*)zx;                   // gemm2 split-K f16 partials

  k_cvt_win<<<4608, 256, 0, stream>>>(W_in, win_f);
  k_cvt    <<<1024, 256, 0, stream>>>(W_out, wout_f);   // 512*2048/1024
  k_keff   <<<9, 256, 0, stream>>>(w33, w13x1, w31x1, w13x2, w31x2,
                                   w13bc1, w31bc1, w13bc2, w31bc2, wz, keffall);

  for (int ch = 0; ch < nch; ++ch) {
    const float* uc   = u + (size_t)ch * Mc * 512;
    float*       outc = (float*)d_out + (size_t)ch * Mc * 512;
    const int ntm = Mc / 128;

    k_cvt<<<Mc/2, 256, 0, stream>>>(uc, u_f);   // u -> f16

    // GEMM1: zx(f16) = u_f @ W_in^T  (N padded to 2304, store-guard 2240)
    k_gemmf<f16><<<ntm*18, 256, 0, stream>>>(u_f, 512, win_f, 512,
                                             zx, DPROJ, 512, DPROJ, 18, ntm*18, 0);

    // fused f16 conv (token-pair x dual-chain) + dA
    k_conv_all<<<Mc/2, 192, 0, stream>>>(zx, keffall, a2, dt_bias, A_log,
                                         xbc, g2, dAb);

    // attention KV (zx arena now dead -> partials live there)
    k_kv_part <<<dim3(128, C), 512, 0, stream>>>(xbc, dAb, part);
    k_kv_red  <<<dim3(64, C), 256, 0, stream>>>(part, KV);
    k_y_ln    <<<C*128, 256, 0, stream>>>(xbc, KV, Dp, ln_g, ln_b, sc, sh, a1, g2);

    // GEMM2: split-K=2 f16 partials in zx arena, then reduce into out
    const long cseg = (long)Mc * 512;
    k_gemmf<f16><<<ntm*4*2, 256, 0, stream>>>(g2, 2048, wout_f, 2048,
                                              kpart, 512, 1024, 512, 4, ntm*4, cseg);
    k_red2h<<<Mc/2, 256, 0, stream>>>(kpart, cseg, outc);
  }
}

// Round 21
// 516.875 us; speedup vs baseline: 1.0928x; 1.0425x over previous
//
#include <hip/hip_runtime.h>
#include <hip/hip_bf16.h>
#include <cstdint>
#include <cstddef>

// ---------------- problem constants ----------------
#define HDIM    64
#define WDIM    64
#define LPB     4096            // tokens per batch
#define DMODEL  512
#define DIN     1024
#define CONVD   1088
#define DPROJ   2240            // 2*DIN + 2*32 + 128
#define NHEADS  128
#define NCV     2112            // conv channels total (z 1024 + xBC 1088)

using f16    = _Float16;
using f16x4  = __attribute__((ext_vector_type(4))) _Float16;
using f16x8  = __attribute__((ext_vector_type(8))) _Float16;
using f32x4  = __attribute__((ext_vector_type(4))) float;

__device__ __forceinline__ float siluf(float x) { return x / (1.f + __expf(-x)); }
// fast silu: rcp instead of IEEE division
__device__ __forceinline__ float fsilu(float x) {
  return x * __builtin_amdgcn_rcpf(1.f + __expf(-x));
}

// acc += f16lo(a) * f16lo(b)  /  acc += f16hi(a) * f16hi(b)   (f32 accumulate)
__device__ __forceinline__ void fma_mix_lo(float& acc, unsigned a, unsigned b) {
  asm("v_fma_mix_f32 %0, %1, %2, %0 op_sel_hi:[1,1,0]" : "+v"(acc) : "v"(a), "v"(b));
}
__device__ __forceinline__ void fma_mix_hi(float& acc, unsigned a, unsigned b) {
  asm("v_fma_mix_f32 %0, %1, %2, %0 op_sel:[1,1,0] op_sel_hi:[1,1,0]" : "+v"(acc) : "v"(a), "v"(b));
}
// acc += f16lo/hi(a) * f32(b)
__device__ __forceinline__ void fmixl(float& acc, unsigned a, float b) {
  asm("v_fma_mix_f32 %0, %1, %2, %0 op_sel_hi:[1,0,0]" : "+v"(acc) : "v"(a), "v"(b));
}
__device__ __forceinline__ void fmixh(float& acc, unsigned a, float b) {
  asm("v_fma_mix_f32 %0, %1, %2, %0 op_sel:[1,0,0] op_sel_hi:[1,0,0]" : "+v"(acc) : "v"(a), "v"(b));
}

// 8-channel fma_mix block: acc[0..7] += v(f16x8) * w(f16x8) in f32
__device__ __forceinline__ void fma8(float* acc, const uint4& v, const uint4& w) {
  fma_mix_lo(acc[0], v.x, w.x);  fma_mix_hi(acc[1], v.x, w.x);
  fma_mix_lo(acc[2], v.y, w.y);  fma_mix_hi(acc[3], v.y, w.y);
  fma_mix_lo(acc[4], v.z, w.z);  fma_mix_hi(acc[5], v.z, w.z);
  fma_mix_lo(acc[6], v.w, w.w);  fma_mix_hi(acc[7], v.w, w.w);
}

// ---------------- f32 -> f16 conversion preps ----------------
__global__ __launch_bounds__(256) void k_cvt(const float* __restrict__ in, f16* __restrict__ out) {
  size_t i = ((size_t)blockIdx.x * 256 + threadIdx.x) * 4;
  f32x4 v = *(const f32x4*)(in + i);
  f16x4 o;
  #pragma unroll
  for (int j = 0; j < 4; ++j) o[j] = (f16)v[j];
  *(f16x4*)(out + i) = o;
}

// W_in with zero-pad to 2304 rows
__global__ __launch_bounds__(256) void k_cvt_win(const float* __restrict__ W, f16* __restrict__ out) {
  int i = blockIdx.x * 256 + threadIdx.x;    // over 2304*512
  int row = i >> 9, col = i & 511;
  float v = (row < DPROJ) ? W[row * 512 + col] : 0.f;
  out[i] = (f16)v;
}

// Effective per-channel 3x3 kernels, transposed f16: keffall[tap][channel c<2112].
__global__ __launch_bounds__(256) void k_keff(const float* __restrict__ w33,
                       const float* __restrict__ w13x1, const float* __restrict__ w31x1,
                       const float* __restrict__ w13x2, const float* __restrict__ w31x2,
                       const float* __restrict__ w13bc1, const float* __restrict__ w31bc1,
                       const float* __restrict__ w13bc2, const float* __restrict__ w31bc2,
                       const float* __restrict__ wz,
                       f16* __restrict__ keffall) {
  int j = blockIdx.x * 256 + threadIdx.x;
  if (j >= NCV) return;
  if (j < 1024) {
    #pragma unroll
    for (int tap = 0; tap < 9; ++tap) keffall[tap * NCV + j] = (f16)wz[j * 9 + tap];
    return;
  }
  int jj = j - 1024;
  float kh[3] = {0,0,0}, kw[3] = {0,0,0};
  bool dense = ((jj & 1) == 0);
  if (!dense) {
    int m = jj >> 2;                      // jj = 4m+1 or 4m+3
    if ((jj & 3) == 1) {
      if (m < 256) { for (int t=0;t<3;++t){ kh[t]=w31x1[m*3+t];  kw[t]=w13x1[m*3+t];  } }
      else { int q=m-256; for (int t=0;t<3;++t){ kh[t]=w31bc1[q*3+t]; kw[t]=w13bc1[q*3+t]; } }
    } else {
      if (m < 256) { for (int t=0;t<3;++t){ kh[t]=w31x2[m*3+t];  kw[t]=w13x2[m*3+t];  } }
      else { int q=m-256; for (int t=0;t<3;++t){ kh[t]=w31bc2[q*3+t]; kw[t]=w13bc2[q*3+t]; } }
    }
  }
  #pragma unroll
  for (int dh = 0; dh < 3; ++dh)
    #pragma unroll
    for (int dw = 0; dw < 3; ++dw) {
      float v = dense ? w33[(jj >> 1) * 9 + dh*3 + dw] : kh[dh] * kw[dw];
      keffall[(dh*3 + dw) * NCV + j] = (f16)v;
    }
}

// ---- single-pass fp16 MFMA GEMM with optional split-K; m97 structure, 128x128 tile ----
template<typename OutT>
__global__ __launch_bounds__(256) void k_gemmf(const f16* __restrict__ A, int lda,
                                               const f16* __restrict__ Bm, int ldb,
                                               OutT* __restrict__ C, int ldc,
                                               int Kseg, int NW, int ntn, int ntmn, long Cseg) {
  __shared__ __align__(16) f16 As[128 * 32];
  __shared__ __align__(16) f16 Bs[128 * 32];

  // bijective chunked XCD swizzle (m204)
  int nwg = gridDim.x, bid = blockIdx.x;
  int q = nwg >> 3, r = nwg & 7;
  int xcd = bid & 7, loc = bid >> 3;
  int wg  = (xcd < r ? xcd * (q + 1) : r * (q + 1) + (xcd - r) * q) + loc;
  int kseg = wg / ntmn;
  int rem  = wg - kseg * ntmn;
  long m0 = (long)(rem / ntn) * 128;
  long n0 = (long)(rem % ntn) * 128;
  const int kbase = kseg * Kseg;

  const int tid  = threadIdx.x;
  const int w    = tid >> 6, lane = tid & 63;
  const int wr   = w >> 1, wc = w & 1;

  f32x4 acc[4][4];
  #pragma unroll
  for (int i = 0; i < 4; ++i)
    #pragma unroll
    for (int j = 0; j < 4; ++j) acc[i][j] = (f32x4){0.f,0.f,0.f,0.f};

  const int srow = w * 16 + (lane >> 2);   // staging row within 64-row half
  const int scol = (lane & 3) * 8;         // 8 f16 = 16B per lane
  const long aoff = (m0 + srow) * (long)lda + scol + kbase;
  const long boff = (n0 + srow) * (long)ldb + scol + kbase;
  const int fr = lane & 15;
  const int kc = (lane >> 4) * 8;

  for (int k0 = 0; k0 < Kseg; k0 += 32) {
    #pragma unroll
    for (int i = 0; i < 2; ++i) {
      long ao = aoff + (long)i*64*lda + k0;
      long bo = boff + (long)i*64*ldb + k0;
      int ls = (i*4 + w) * 512;
      __builtin_amdgcn_global_load_lds((const __attribute__((address_space(1))) void*)(A + ao),
                                       (__attribute__((address_space(3))) void*)&As[ls], 16, 0, 0);
      __builtin_amdgcn_global_load_lds((const __attribute__((address_space(1))) void*)(Bm + bo),
                                       (__attribute__((address_space(3))) void*)&Bs[ls], 16, 0, 0);
    }
    __syncthreads();
    f16x8 af[4], bf[4];
    #pragma unroll
    for (int f = 0; f < 4; ++f) {
      af[f] = *(const f16x8*)&As[(wr*64 + f*16 + fr) * 32 + kc];
      bf[f] = *(const f16x8*)&Bs[(wc*64 + f*16 + fr) * 32 + kc];
    }
    #pragma unroll
    for (int i = 0; i < 4; ++i)
      #pragma unroll
      for (int j = 0; j < 4; ++j)
        acc[i][j] = __builtin_amdgcn_mfma_f32_16x16x32_f16(af[i], bf[j], acc[i][j], 0, 0, 0);
    __syncthreads();
  }

  OutT* Cb = C + (long)kseg * Cseg;
  const int cr = (lane >> 4) * 4;          // C/D: row=(lane>>4)*4+reg, col=lane&15
  const int cc = lane & 15;
  #pragma unroll
  for (int i = 0; i < 4; ++i) {
    long rbase = m0 + wr*64 + i*16 + cr;
    #pragma unroll
    for (int j = 0; j < 4; ++j) {
      int col = (int)n0 + wc*64 + j*16 + cc;
      if (col < NW) {
        OutT* cp = Cb + rbase * (long)ldc + col;
        #pragma unroll
        for (int r2 = 0; r2 < 4; ++r2) cp[(long)r2 * ldc] = (OutT)acc[i][j][r2];
      }
    }
  }
}

// ------ fused f16 conv: TOKEN-PAIR x dual-chain. Block = 2 adjacent w-tokens. ------
// 192 threads: t<132 conv (16ch x 2 tokens), t in [132,164) dA (8 heads x token).
__global__ __launch_bounds__(192) void k_conv_all(const f16* __restrict__ zx,
                                                  const f16* __restrict__ keffall,
                                                  const float* __restrict__ a2_p,
                                                  const float* __restrict__ dt_bias,
                                                  const float* __restrict__ A_log,
                                                  f16* __restrict__ xbc,
                                                  f16* __restrict__ g2,
                                                  float* __restrict__ dAb) {
  int t = threadIdx.x;
  // XCD-chunk swizzle over token pairs (gridDim.x % 8 == 0)
  int bid = blockIdx.x, qq = gridDim.x >> 3;
  int grp = (bid & 7) * qq + (bid >> 3);
  int l0 = grp * 2;                          // even token; pair shares image row
  long lb = (long)(l0 & ~(LPB - 1));         // batch base row
  int h  = (l0 >> 6) & 63;
  int w0 = l0 & 63;                          // even, 0..62

  if (t < 132) {
    int c0 = t * 8;                          // [0,1056)
    int c1 = c0 + 1056;                      // [1056,2112)
    float a00[8] = {0,0,0,0,0,0,0,0};        // token0 chain0
    float a01[8] = {0,0,0,0,0,0,0,0};        // token0 chain1
    float a10[8] = {0,0,0,0,0,0,0,0};        // token1 chain0
    float a11[8] = {0,0,0,0,0,0,0,0};        // token1 chain1
    const uint4 z4 = {0u,0u,0u,0u};

    #pragma unroll
    for (int dh = 0; dh < 3; ++dh) {
      int hh = h + dh - 1;
      if (hh < 0 || hh >= HDIM) continue;    // block-uniform
      const f16* rp = zx + (lb + (long)(hh * 64)) * DPROJ;
      uint4 v0[4], v1[4];
      #pragma unroll
      for (int pp = 0; pp < 4; ++pp) {       // positions w0-1 .. w0+2
        int ww = w0 + pp - 1;
        ww = ww < 0 ? 0 : (ww > 63 ? 63 : ww);
        const f16* tp = rp + (long)ww * DPROJ;
        v0[pp] = *(const uint4*)(tp + c0);
        v1[pp] = *(const uint4*)(tp + c1);
      }
      if (w0 == 0)  { v0[0] = z4; v1[0] = z4; }   // block-uniform edge zeroing
      if (w0 == 62) { v0[3] = z4; v1[3] = z4; }
      #pragma unroll
      for (int dw = 0; dw < 3; ++dw) {
        uint4 wa = *(const uint4*)&keffall[(dh*3 + dw) * NCV + c0];
        uint4 wb = *(const uint4*)&keffall[(dh*3 + dw) * NCV + c1];
        fma8(a00, v0[dw],     wa);           // token0 uses positions dw
        fma8(a10, v0[dw + 1], wa);           // token1 uses positions dw+1
        fma8(a01, v1[dw],     wb);
        fma8(a11, v1[dw + 1], wb);
      }
    }

    float a2 = a2_p[0];
    #pragma unroll
    for (int ti = 0; ti < 2; ++ti) {
      long l = l0 + ti;
      const float* pc0 = ti ? a10 : a00;
      const float* pc1 = ti ? a11 : a01;
      f16x8 o8;
      if (c0 < 1024) {                       // chain0 -> z region
        #pragma unroll
        for (int j = 0; j < 8; ++j) o8[j] = (f16)(a2 * fsilu(pc0[j]));
        *(f16x8*)&g2[l * 2048 + 1024 + c0] = o8;
      } else {                               // chain0 tail -> xbc
        #pragma unroll
        for (int j = 0; j < 8; ++j) o8[j] = (f16)fsilu(pc0[j]);
        *(f16x8*)&xbc[l * (long)CONVD + (c0 - 1024)] = o8;
      }
      f16x8 o9;
      #pragma unroll
      for (int j = 0; j < 8; ++j) o9[j] = (f16)fsilu(pc1[j]);
      *(f16x8*)&xbc[l * (long)CONVD + (c1 - 1024)] = o9;
    }
  } else if (t < 164) {                      // dA: 32 threads = 2 tokens x 16 x 8 heads
    int idx = t - 132;
    int ti = idx >> 4;
    int hd = (idx & 15) * 8;
    long l = l0 + ti;
    f16x8 x = *(const f16x8*)&zx[l * (long)DPROJ + NCV + hd];
    f32x4 o0, o1;
    #pragma unroll
    for (int j = 0; j < 8; ++j) {
      float xx = (float)x[j] + dt_bias[hd + j];
      float sp = (xx > 20.f) ? xx : log1pf(__expf(xx));
      float dv = sp * __expf(A_log[hd + j]);
      if (j < 4) o0[j] = dv; else o1[j-4] = dv;
    }
    *(f32x4*)&dAb[l * 128 + hd]     = o0;
    *(f32x4*)&dAb[l * 128 + hd + 4] = o1;
  }
}

// ---------------- KV partials over 32-token slices (vectorized B loads) ----------------
__global__ __launch_bounds__(512) void k_kv_part(const f16* __restrict__ xbc,
                                                 const float* __restrict__ dA,
                                                 float* __restrict__ part) {
  int t = threadIdx.x;
  int m = t >> 3, p = t & 7;                 // m: head-pair 0..63, p: headdim 0..7
  int lc = blockIdx.x, b = blockIdx.y;       // lc: 0..127 (32 tokens each), b chunk-local
  float acc0[16], acc1[16];
  #pragma unroll
  for (int s = 0; s < 16; ++s) { acc0[s] = 0.f; acc1[s] = 0.f; }
  long lbase = (long)b * LPB + lc * 32;
  #pragma unroll 2
  for (int li = 0; li < 32; ++li) {
    long row = lbase + li;
    const f16* xr = xbc + row * CONVD;
    float2 aa = *(const float2*)&dA[row * 128 + 2*m];        // dA heads 2m, 2m+1
    float xv0 = (float)xr[16*m + p]     * aa.x;              // head 2m   (group 0)
    float xv1 = (float)xr[16*m + 8 + p] * aa.y;              // head 2m+1 (group 1)
    uint4 q0 = *(const uint4*)(xr + DIN);                    // B g0 s0..7
    uint4 q1 = *(const uint4*)(xr + DIN + 8);                // B g0 s8..15
    uint4 q2 = *(const uint4*)(xr + DIN + 16);               // B g1 s0..7
    uint4 q3 = *(const uint4*)(xr + DIN + 24);               // B g1 s8..15
    unsigned a0[4] = {q0.x, q0.y, q0.z, q0.w};
    unsigned a1[4] = {q1.x, q1.y, q1.z, q1.w};
    unsigned a2v[4] = {q2.x, q2.y, q2.z, q2.w};
    unsigned a3[4] = {q3.x, q3.y, q3.z, q3.w};
    #pragma unroll
    for (int k = 0; k < 4; ++k) {
      fmixl(acc0[2*k],     a0[k], xv0);  fmixh(acc0[2*k+1],     a0[k], xv0);
      fmixl(acc0[8+2*k],   a1[k], xv0);  fmixh(acc0[8+2*k+1],   a1[k], xv0);
      fmixl(acc1[2*k],     a2v[k], xv1); fmixh(acc1[2*k+1],     a2v[k], xv1);
      fmixl(acc1[8+2*k],   a3[k], xv1);  fmixh(acc1[8+2*k+1],   a3[k], xv1);
    }
  }
  long base = ((long)(b*128 + lc)) * 16384 + (long)m * 256;
  #pragma unroll
  for (int s = 0; s < 16; ++s) {
    part[base + s*8 + p]       = acc0[s];
    part[base + 128 + s*8 + p] = acc1[s];
  }
}

__global__ __launch_bounds__(256) void k_kv_red(const float* __restrict__ part,
                                                float* __restrict__ KV) {
  int e = blockIdx.x * 256 + threadIdx.x;   // 16384 per b
  int b = blockIdx.y;
  float s = 0.f;
  #pragma unroll 4
  for (int lc = 0; lc < 128; ++lc) s += part[((long)(b*128 + lc)) * 16384 + e];
  KV[(long)b * 16384 + e] = s;
}

// --- y = Q*KV + x*Dp, LayerNorm, scale/shift, *alpha1 -> g2 cols [0,1024) f16 ---
__global__ __launch_bounds__(256) void k_y_ln(const f16* __restrict__ xbc,
                                              const float* __restrict__ KV,
                                              const float* __restrict__ Dp,
                                              const float* __restrict__ ln_g,
                                              const float* __restrict__ ln_b,
                                              const float* __restrict__ sc_p,
                                              const float* __restrict__ sh_p,
                                              const float* __restrict__ a1_p,
                                              f16* __restrict__ g2) {
  __shared__ float Qs[32][32];
  __shared__ float red[2][8];
  int t = threadIdx.x;
  int hd = t >> 1, pb = (t & 1) * 4;
  int m = hd >> 1, g = hd & 1;
  int b = blockIdx.x >> 7;                  // chunk-local batch (128 groups/batch)
  long l0 = (long)b * LPB + (blockIdx.x & 127) * 32;

  f32x4 kv[16];
  #pragma unroll
  for (int s = 0; s < 16; ++s)
    kv[s] = *(const f32x4*)&KV[(long)b * 16384 + m*256 + g*128 + s*8 + pb];

  if (t < 128) {                            // vectorized Q staging: 128 x f16x8
    int tok = t >> 2, q8 = (t & 3) * 8;
    f16x8 qv = *(const f16x8*)&xbc[(l0 + tok) * CONVD + 1056 + q8];
    #pragma unroll
    for (int j = 0; j < 8; ++j) Qs[tok][q8 + j] = (float)qv[j];
  }
  int c0 = hd*8 + pb;
  f32x4 lg = *(const f32x4*)&ln_g[c0];
  f32x4 lb = *(const f32x4*)&ln_b[c0];
  float dpv = Dp[hd];
  float sc = sc_p[0], sh = sh_p[0], a1 = a1_p[0];
  int wv = t >> 6, lane = t & 63;
  __syncthreads();

  for (int tok = 0; tok < 32; ++tok) {
    long row = l0 + tok;
    f16x4 xr4 = *(const f16x4*)&xbc[row * CONVD + c0];
    f32x4 yv;
    #pragma unroll
    for (int j = 0; j < 4; ++j) yv[j] = (float)xr4[j] * dpv;
    #pragma unroll
    for (int s = 0; s < 16; ++s) {
      float qv = Qs[tok][g*16 + s];
      #pragma unroll
      for (int j = 0; j < 4; ++j) yv[j] = fmaf(qv, kv[s][j], yv[j]);
    }
    float s1 = yv[0] + yv[1] + yv[2] + yv[3];
    float s2 = yv[0]*yv[0] + yv[1]*yv[1] + yv[2]*yv[2] + yv[3]*yv[3];
    #pragma unroll
    for (int off = 1; off < 64; off <<= 1) {
      s1 += __shfl_xor(s1, off, 64);
      s2 += __shfl_xor(s2, off, 64);
    }
    if (lane == 0) { red[tok & 1][wv*2] = s1; red[tok & 1][wv*2 + 1] = s2; }
    __syncthreads();                        // single barrier (parity buffer)
    const float* rr = red[tok & 1];
    float S1 = rr[0] + rr[2] + rr[4] + rr[6];
    float S2 = rr[1] + rr[3] + rr[5] + rr[7];
    float mu   = S1 * (1.f/1024.f);
    float var  = S2 * (1.f/1024.f) - mu*mu;
    float rstd = rsqrtf(var + 1e-5f);
    f16x4 o4;
    #pragma unroll
    for (int j = 0; j < 4; ++j) {
      float yn = (yv[j] - mu) * rstd * lg[j] + lb[j];
      o4[j] = (f16)(a1 * (yn * sc + sh));
    }
    *(f16x4*)&g2[row * 2048 + c0] = o4;
  }
}

// ---------------- host launcher ----------------
extern "C" void kernel_launch(void* const* d_in, const int* in_sizes, int n_in,
                              void* d_out, int out_size, void* d_ws, size_t ws_size,
                              hipStream_t stream) {
  const float* u       = (const float*)d_in[0];
  const float* W_in    = (const float*)d_in[3];
  const float* dt_bias = (const float*)d_in[4];
  const float* A_log   = (const float*)d_in[5];
  const float* Dp      = (const float*)d_in[6];
  const float* w33     = (const float*)d_in[7];
  const float* w13x1   = (const float*)d_in[8];
  const float* w31x1   = (const float*)d_in[9];
  const float* w13x2   = (const float*)d_in[10];
  const float* w31x2   = (const float*)d_in[11];
  const float* w13bc1  = (const float*)d_in[12];
  const float* w31bc1  = (const float*)d_in[13];
  const float* w13bc2  = (const float*)d_in[14];
  const float* w31bc2  = (const float*)d_in[15];
  const float* wz      = (const float*)d_in[16];
  const float* ln_g    = (const float*)d_in[17];
  const float* ln_b    = (const float*)d_in[18];
  const float* sc      = (const float*)d_in[19];
  const float* sh      = (const float*)d_in[20];
  const float* a1      = (const float*)d_in[21];
  const float* a2      = (const float*)d_in[22];
  const float* W_out   = (const float*)d_in[23];

  // per-batch buffer bytes (u_f16 aliases g2; kv partials live in zx)
  const size_t B_G2   = 16777216;   // 4096x2048 f16
  const size_t B_ZX   = 18350080;   // 4096x2240 f16
  const size_t B_XBC  = 8912896;    // 4096x1088 f16
  const size_t B_DA   = 2097152;    // 4096x128 f32
  const size_t B_KV   = 65536;      // 16384 f32
  const size_t perC   = B_G2 + B_ZX + B_XBC + B_DA + B_KV;   // 46.2 MB
  const size_t persist = 2359296 + 2097152 + 38912;

  int C = 8;
  while (C > 1 && persist + (size_t)C * perC > ws_size) C >>= 1;
  const int nch = 8 / C;
  const int Mc  = C * LPB;

  char* p = (char*)d_ws;
  f16*   win_f   = (f16*)p;   p += 2359296;   // 2304x512
  f16*   wout_f  = (f16*)p;   p += 2097152;   // 512x2048
  f16*   keffall = (f16*)p;   p += 38912;     // 9x2112 f16 (padded)
  char*  arena   = p;                          // u_f16 aliases g2 (conv rewrites it later)
  f16*   g2      = (f16*)arena;
  f16*   u_f     = (f16*)arena;
  p = arena + (size_t)C * B_G2;
  f16*   zx      = (f16*)p;   p += (size_t)C * B_ZX;
  f16*   xbc     = (f16*)p;   p += (size_t)C * B_XBC;
  float* dAb     = (float*)p; p += (size_t)C * B_DA;
  float* KV      = (float*)p; p += (size_t)C * B_KV;
  float* part   = (float*)zx;                 // kv partials (after conv, zx dead)

  k_cvt_win<<<4608, 256, 0, stream>>>(W_in, win_f);
  k_cvt    <<<1024, 256, 0, stream>>>(W_out, wout_f);   // 512*2048/1024
  k_keff   <<<9, 256, 0, stream>>>(w33, w13x1, w31x1, w13x2, w31x2,
                                   w13bc1, w31bc1, w13bc2, w31bc2, wz, keffall);

  for (int ch = 0; ch < nch; ++ch) {
    const float* uc   = u + (size_t)ch * Mc * 512;
    float*       outc = (float*)d_out + (size_t)ch * Mc * 512;
    const int ntm = Mc / 128;

    k_cvt<<<Mc/2, 256, 0, stream>>>(uc, u_f);   // u -> f16

    // GEMM1: zx(f16) = u_f @ W_in^T  (N padded to 2304, store-guard 2240)
    k_gemmf<f16><<<ntm*18, 256, 0, stream>>>(u_f, 512, win_f, 512,
                                             zx, DPROJ, 512, DPROJ, 18, ntm*18, 0);

    // fused f16 conv (token-pair x dual-chain) + dA
    k_conv_all<<<Mc/2, 192, 0, stream>>>(zx, keffall, a2, dt_bias, A_log,
                                         xbc, g2, dAb);

    // attention KV (zx arena now dead -> partials live there)
    k_kv_part <<<dim3(128, C), 512, 0, stream>>>(xbc, dAb, part);
    k_kv_red  <<<dim3(64, C), 256, 0, stream>>>(part, KV);
    k_y_ln    <<<C*128, 256, 0, stream>>>(xbc, KV, Dp, ln_g, ln_b, sc, sh, a1, g2);

    // GEMM2: direct f32 write, full K=2048, no split-K / no reduction pass
    k_gemmf<float><<<ntm*4, 256, 0, stream>>>(g2, 2048, wout_f, 2048,
                                              outc, 512, 2048, 512, 4, ntm*4, 0);
  }
}

// Round 22
// 505.690 us; speedup vs baseline: 1.1170x; 1.0221x over previous
//
#include <hip/hip_runtime.h>
#include <hip/hip_bf16.h>
#include <cstdint>
#include <cstddef>

// ---------------- problem constants ----------------
#define HDIM    64
#define WDIM    64
#define LPB     4096            // tokens per batch
#define DMODEL  512
#define DIN     1024
#define CONVD   1088
#define DPROJ   2240            // 2*DIN + 2*32 + 128
#define NHEADS  128
#define NCV     2112            // conv channels total (z 1024 + xBC 1088)

using f16    = _Float16;
using f16x4  = __attribute__((ext_vector_type(4))) _Float16;
using f16x8  = __attribute__((ext_vector_type(8))) _Float16;
using f32x4  = __attribute__((ext_vector_type(4))) float;

#define VM_CNT(n) asm volatile("s_waitcnt vmcnt(" #n ")" ::: "memory")
#define LDSFENCE  asm volatile("" ::: "memory")

__device__ __forceinline__ float siluf(float x) { return x / (1.f + __expf(-x)); }
__device__ __forceinline__ float fsilu(float x) {
  return x * __builtin_amdgcn_rcpf(1.f + __expf(-x));
}

// acc += f16lo(a)*f16lo(b) / hi*hi (f32 accumulate)
__device__ __forceinline__ void fma_mix_lo(float& acc, unsigned a, unsigned b) {
  asm("v_fma_mix_f32 %0, %1, %2, %0 op_sel_hi:[1,1,0]" : "+v"(acc) : "v"(a), "v"(b));
}
__device__ __forceinline__ void fma_mix_hi(float& acc, unsigned a, unsigned b) {
  asm("v_fma_mix_f32 %0, %1, %2, %0 op_sel:[1,1,0] op_sel_hi:[1,1,0]" : "+v"(acc) : "v"(a), "v"(b));
}
__device__ __forceinline__ void fmixl(float& acc, unsigned a, float b) {
  asm("v_fma_mix_f32 %0, %1, %2, %0 op_sel_hi:[1,0,0]" : "+v"(acc) : "v"(a), "v"(b));
}
__device__ __forceinline__ void fmixh(float& acc, unsigned a, float b) {
  asm("v_fma_mix_f32 %0, %1, %2, %0 op_sel:[1,0,0] op_sel_hi:[1,0,0]" : "+v"(acc) : "v"(a), "v"(b));
}
__device__ __forceinline__ void fma8(float* acc, const uint4& v, const uint4& w) {
  fma_mix_lo(acc[0], v.x, w.x);  fma_mix_hi(acc[1], v.x, w.x);
  fma_mix_lo(acc[2], v.y, w.y);  fma_mix_hi(acc[3], v.y, w.y);
  fma_mix_lo(acc[4], v.z, w.z);  fma_mix_hi(acc[5], v.z, w.z);
  fma_mix_lo(acc[6], v.w, w.w);  fma_mix_hi(acc[7], v.w, w.w);
}

// ---------------- f32 -> f16 conversion preps ----------------
__global__ __launch_bounds__(256) void k_cvt(const float* __restrict__ in, f16* __restrict__ out) {
  size_t i = ((size_t)blockIdx.x * 256 + threadIdx.x) * 4;
  f32x4 v = *(const f32x4*)(in + i);
  f16x4 o;
  #pragma unroll
  for (int j = 0; j < 4; ++j) o[j] = (f16)v[j];
  *(f16x4*)(out + i) = o;
}

// W_in with zero-pad to 2304 rows
__global__ __launch_bounds__(256) void k_cvt_win(const float* __restrict__ W, f16* __restrict__ out) {
  int i = blockIdx.x * 256 + threadIdx.x;    // over 2304*512
  int row = i >> 9, col = i & 511;
  float v = (row < DPROJ) ? W[row * 512 + col] : 0.f;
  out[i] = (f16)v;
}

// Effective per-channel 3x3 kernels, transposed f16: keffall[tap][channel c<2112].
__global__ __launch_bounds__(256) void k_keff(const float* __restrict__ w33,
                       const float* __restrict__ w13x1, const float* __restrict__ w31x1,
                       const float* __restrict__ w13x2, const float* __restrict__ w31x2,
                       const float* __restrict__ w13bc1, const float* __restrict__ w31bc1,
                       const float* __restrict__ w13bc2, const float* __restrict__ w31bc2,
                       const float* __restrict__ wz,
                       f16* __restrict__ keffall) {
  int j = blockIdx.x * 256 + threadIdx.x;
  if (j >= NCV) return;
  if (j < 1024) {
    #pragma unroll
    for (int tap = 0; tap < 9; ++tap) keffall[tap * NCV + j] = (f16)wz[j * 9 + tap];
    return;
  }
  int jj = j - 1024;
  float kh[3] = {0,0,0}, kw[3] = {0,0,0};
  bool dense = ((jj & 1) == 0);
  if (!dense) {
    int m = jj >> 2;                      // jj = 4m+1 or 4m+3
    if ((jj & 3) == 1) {
      if (m < 256) { for (int t=0;t<3;++t){ kh[t]=w31x1[m*3+t];  kw[t]=w13x1[m*3+t];  } }
      else { int q=m-256; for (int t=0;t<3;++t){ kh[t]=w31bc1[q*3+t]; kw[t]=w13bc1[q*3+t]; } }
    } else {
      if (m < 256) { for (int t=0;t<3;++t){ kh[t]=w31x2[m*3+t];  kw[t]=w13x2[m*3+t];  } }
      else { int q=m-256; for (int t=0;t<3;++t){ kh[t]=w31bc2[q*3+t]; kw[t]=w13bc2[q*3+t]; } }
    }
  }
  #pragma unroll
  for (int dh = 0; dh < 3; ++dh)
    #pragma unroll
    for (int dw = 0; dw < 3; ++dw) {
      float v = dense ? w33[(jj >> 1) * 9 + dh*3 + dw] : kh[dh] * kw[dw];
      keffall[(dh*3 + dw) * NCV + j] = (f16)v;
    }
}

// ---- single-pass fp16 MFMA GEMM; m97 structure, 128x128 tile (GEMM1) ----
template<typename OutT>
__global__ __launch_bounds__(256) void k_gemmf(const f16* __restrict__ A, int lda,
                                               const f16* __restrict__ Bm, int ldb,
                                               OutT* __restrict__ C, int ldc,
                                               int Kseg, int NW, int ntn, int ntmn, long Cseg) {
  __shared__ __align__(16) f16 As[128 * 32];
  __shared__ __align__(16) f16 Bs[128 * 32];

  // bijective chunked XCD swizzle (m204)
  int nwg = gridDim.x, bid = blockIdx.x;
  int q = nwg >> 3, r = nwg & 7;
  int xcd = bid & 7, loc = bid >> 3;
  int wg  = (xcd < r ? xcd * (q + 1) : r * (q + 1) + (xcd - r) * q) + loc;
  int kseg = wg / ntmn;
  int rem  = wg - kseg * ntmn;
  long m0 = (long)(rem / ntn) * 128;
  long n0 = (long)(rem % ntn) * 128;
  const int kbase = kseg * Kseg;

  const int tid  = threadIdx.x;
  const int w    = tid >> 6, lane = tid & 63;
  const int wr   = w >> 1, wc = w & 1;

  f32x4 acc[4][4];
  #pragma unroll
  for (int i = 0; i < 4; ++i)
    #pragma unroll
    for (int j = 0; j < 4; ++j) acc[i][j] = (f32x4){0.f,0.f,0.f,0.f};

  const int srow = w * 16 + (lane >> 2);   // staging row within 64-row half
  const int scol = (lane & 3) * 8;         // 8 f16 = 16B per lane
  const long aoff = (m0 + srow) * (long)lda + scol + kbase;
  const long boff = (n0 + srow) * (long)ldb + scol + kbase;
  const int fr = lane & 15;
  const int kc = (lane >> 4) * 8;

  for (int k0 = 0; k0 < Kseg; k0 += 32) {
    #pragma unroll
    for (int i = 0; i < 2; ++i) {
      long ao = aoff + (long)i*64*lda + k0;
      long bo = boff + (long)i*64*ldb + k0;
      int ls = (i*4 + w) * 512;
      __builtin_amdgcn_global_load_lds((const __attribute__((address_space(1))) void*)(A + ao),
                                       (__attribute__((address_space(3))) void*)&As[ls], 16, 0, 0);
      __builtin_amdgcn_global_load_lds((const __attribute__((address_space(1))) void*)(Bm + bo),
                                       (__attribute__((address_space(3))) void*)&Bs[ls], 16, 0, 0);
    }
    __syncthreads();
    f16x8 af[4], bf[4];
    #pragma unroll
    for (int f = 0; f < 4; ++f) {
      af[f] = *(const f16x8*)&As[(wr*64 + f*16 + fr) * 32 + kc];
      bf[f] = *(const f16x8*)&Bs[(wc*64 + f*16 + fr) * 32 + kc];
    }
    #pragma unroll
    for (int i = 0; i < 4; ++i)
      #pragma unroll
      for (int j = 0; j < 4; ++j)
        acc[i][j] = __builtin_amdgcn_mfma_f32_16x16x32_f16(af[i], bf[j], acc[i][j], 0, 0, 0);
    __syncthreads();
  }

  OutT* Cb = C + (long)kseg * Cseg;
  const int cr = (lane >> 4) * 4;          // C/D: row=(lane>>4)*4+reg, col=lane&15
  const int cc = lane & 15;
  #pragma unroll
  for (int i = 0; i < 4; ++i) {
    long rbase = m0 + wr*64 + i*16 + cr;
    #pragma unroll
    for (int j = 0; j < 4; ++j) {
      int col = (int)n0 + wc*64 + j*16 + cc;
      if (col < NW) {
        OutT* cp = Cb + rbase * (long)ldc + col;
        #pragma unroll
        for (int r2 = 0; r2 < 4; ++r2) cp[(long)r2 * ldc] = (OutT)acc[i][j][r2];
      }
    }
  }
}

// ======== 8-phase 256x256 fp16 GEMM (r16-verified schedule) + split-K (GEMM2) ========
// 512 threads = 8 waves (2M x 4N). BK=64, double-buffered LDS, chunk^row&7 XOR
// swizzle, counted vmcnt(4)/(6). Split-K: kseg offsets the K-base; partial out f16.
__global__ __launch_bounds__(512, 1) void k_gemm8(const f16* __restrict__ A, int lda,
                                                  const f16* __restrict__ Bm, int ldb,
                                                  f16* __restrict__ C, int ldc,
                                                  int Kseg, int NW, int ntn, int ntmn, long Cseg) {
  __shared__ __align__(16) f16 Al[2 * 16384];
  __shared__ __align__(16) f16 Bl[2 * 16384];

  int nwg = gridDim.x, bid = blockIdx.x;
  int q = nwg >> 3, r = nwg & 7;
  int xcd = bid & 7, loc = bid >> 3;
  int wg  = (xcd < r ? xcd * (q + 1) : r * (q + 1) + (xcd - r) * q) + loc;
  int kseg = wg / ntmn;
  int rem  = wg - kseg * ntmn;
  long m0 = (long)(rem / ntn) * 256;
  long n0 = (long)(rem % ntn) * 256;
  const f16* Ab = A + (long)kseg * Kseg;   // K-base offset for this split
  const f16* Bb = Bm + (long)kseg * Kseg;

  const int tid  = threadIdx.x;
  const int wid  = tid >> 6, lane = tid & 63;
  const int wr   = wid >> 2, wc = wid & 3;

  const int rowoff = wid * 8 + (lane >> 3);
  const int scolS  = ((lane & 7) ^ (lane >> 3)) * 8;
  const int ldst   = wid * 512;

  const int fr   = lane & 15;
  const int koff = (lane >> 4) * 8;
  const int swz8 = (lane & 7) << 3;

  f32x4 acc[8][4];
  #pragma unroll
  for (int i = 0; i < 8; ++i)
    #pragma unroll
    for (int j = 0; j < 4; ++j) acc[i][j] = (f32x4){0.f,0.f,0.f,0.f};

  const int NT = Kseg >> 6;

  auto stA = [&](int par, int X, int kb) {
    __builtin_amdgcn_global_load_lds(
      (const __attribute__((address_space(1))) void*)(Ab + (m0 + X*64 + rowoff) * (long)lda + kb + scolS),
      (__attribute__((address_space(3))) void*)&Al[par*16384 + X*4096 + ldst], 16, 0, 0);
  };
  auto stB = [&](int par, int X, int kb) {
    __builtin_amdgcn_global_load_lds(
      (const __attribute__((address_space(1))) void*)(Bb + (n0 + X*64 + rowoff) * (long)ldb + kb + scolS),
      (__attribute__((address_space(3))) void*)&Bl[par*16384 + X*4096 + ldst], 16, 0, 0);
  };

  // prologue: tile 0 into parity 0; issue order B0,B1,B2,B3,A0,A2,A1,A3 (count math!)
  stB(0,0,0); stB(0,1,0); stB(0,2,0); stB(0,3,0);
  stA(0,0,0); stA(0,2,0); stA(0,1,0); stA(0,3,0);

  for (int t = 0; t < NT; ++t) {
    const bool last = (t == NT - 1);
    const int pr = t & 1, pw = (t + 1) & 1;
    const int kb = (t + 1) << 6;
    const f16* Ard = &Al[pr * 16384];
    const f16* Brd = &Bl[pr * 16384];
    f16x8 bf[4][2];

    #pragma unroll
    for (int s = 0; s < 4; ++s) {
      f16x8 af[2][2];
      if (s == 1 || s == 3) {
        #pragma unroll
        for (int j = 0; j < 2; ++j)
          #pragma unroll
          for (int k = 0; k < 2; ++k) {
            int rr = wr*128 + (2*s + j)*16 + fr;
            af[j][k] = *(const f16x8*)&Ard[rr*64 + ((k*32 + koff) ^ swz8)];
          }
      }
      if (!last) {
        if (s == 0)      { stB(pw, 0, kb); stB(pw, 1, kb); }
        else if (s == 1) { stB(pw, 2, kb); stB(pw, 3, kb); }
        else if (s == 2) { stA(pw, 0, kb); stA(pw, 2, kb); }
        else             { stA(pw, 1, kb); stA(pw, 3, kb); }
      }
      if (s == 0) { if (!last) { VM_CNT(4); } else { VM_CNT(2); } }
      if (s == 2) { if (!last) { VM_CNT(6); } else { VM_CNT(0); } }
      __builtin_amdgcn_s_barrier();
      LDSFENCE;
      if (s == 0) {
        #pragma unroll
        for (int ni = 0; ni < 4; ++ni)
          #pragma unroll
          for (int k = 0; k < 2; ++k) {
            int rr = wc*64 + ni*16 + fr;
            bf[ni][k] = *(const f16x8*)&Brd[rr*64 + ((k*32 + koff) ^ swz8)];
          }
      }
      if (s == 0 || s == 2) {
        #pragma unroll
        for (int j = 0; j < 2; ++j)
          #pragma unroll
          for (int k = 0; k < 2; ++k) {
            int rr = wr*128 + (2*s + j)*16 + fr;
            af[j][k] = *(const f16x8*)&Ard[rr*64 + ((k*32 + koff) ^ swz8)];
          }
      }
      __builtin_amdgcn_s_setprio(1);
      #pragma unroll
      for (int j = 0; j < 2; ++j)
        #pragma unroll
        for (int ni = 0; ni < 4; ++ni)
          #pragma unroll
          for (int k = 0; k < 2; ++k)
            acc[2*s + j][ni] = __builtin_amdgcn_mfma_f32_16x16x32_f16(af[j][k], bf[ni][k], acc[2*s + j][ni], 0, 0, 0);
      __builtin_amdgcn_s_setprio(0);
      __builtin_amdgcn_s_barrier();
      LDSFENCE;
    }
  }

  f16* Cb = C + (long)kseg * Cseg;
  const int cr = (lane >> 4) * 4;
  const int cc = lane & 15;
  #pragma unroll
  for (int mi = 0; mi < 8; ++mi) {
    long rbase = m0 + wr*128 + mi*16 + cr;
    #pragma unroll
    for (int ni = 0; ni < 4; ++ni) {
      int col = (int)n0 + wc*64 + ni*16 + cc;
      if (col < NW) {
        f16* cp = Cb + rbase * (long)ldc + col;
        #pragma unroll
        for (int rr2 = 0; rr2 < 4; ++rr2) cp[(long)rr2 * ldc] = (f16)acc[mi][ni][rr2];
      }
    }
  }
}

// ---------------- split-K reduction: out(f32) = sum of 2 f16 partials ----------------
__global__ __launch_bounds__(256) void k_red2h(const f16* __restrict__ part, long seg,
                                               float* __restrict__ out) {
  long i = ((long)blockIdx.x * 256 + threadIdx.x) * 4;
  f16x4 s0 = *(const f16x4*)(part + i);
  f16x4 s1 = *(const f16x4*)(part + seg + i);
  f32x4 o;
  #pragma unroll
  for (int j = 0; j < 4; ++j) o[j] = (float)s0[j] + (float)s1[j];
  *(f32x4*)(out + i) = o;
}

// ------ fused f16 conv: TOKEN-PAIR x dual-chain (r14 form) ------
__global__ __launch_bounds__(192) void k_conv_all(const f16* __restrict__ zx,
                                                  const f16* __restrict__ keffall,
                                                  const float* __restrict__ a2_p,
                                                  const float* __restrict__ dt_bias,
                                                  const float* __restrict__ A_log,
                                                  f16* __restrict__ xbc,
                                                  f16* __restrict__ g2,
                                                  float* __restrict__ dAb) {
  int t = threadIdx.x;
  int bid = blockIdx.x, qq = gridDim.x >> 3;
  int grp = (bid & 7) * qq + (bid >> 3);
  int l0 = grp * 2;
  long lb = (long)(l0 & ~(LPB - 1));
  int h  = (l0 >> 6) & 63;
  int w0 = l0 & 63;

  if (t < 132) {
    int c0 = t * 8;
    int c1 = c0 + 1056;
    float a00[8] = {0,0,0,0,0,0,0,0};
    float a01[8] = {0,0,0,0,0,0,0,0};
    float a10[8] = {0,0,0,0,0,0,0,0};
    float a11[8] = {0,0,0,0,0,0,0,0};
    const uint4 z4 = {0u,0u,0u,0u};

    #pragma unroll
    for (int dh = 0; dh < 3; ++dh) {
      int hh = h + dh - 1;
      if (hh < 0 || hh >= HDIM) continue;
      const f16* rp = zx + (lb + (long)(hh * 64)) * DPROJ;
      uint4 v0[4], v1[4];
      #pragma unroll
      for (int pp = 0; pp < 4; ++pp) {
        int ww = w0 + pp - 1;
        ww = ww < 0 ? 0 : (ww > 63 ? 63 : ww);
        const f16* tp = rp + (long)ww * DPROJ;
        v0[pp] = *(const uint4*)(tp + c0);
        v1[pp] = *(const uint4*)(tp + c1);
      }
      if (w0 == 0)  { v0[0] = z4; v1[0] = z4; }
      if (w0 == 62) { v0[3] = z4; v1[3] = z4; }
      #pragma unroll
      for (int dw = 0; dw < 3; ++dw) {
        uint4 wa = *(const uint4*)&keffall[(dh*3 + dw) * NCV + c0];
        uint4 wb = *(const uint4*)&keffall[(dh*3 + dw) * NCV + c1];
        fma8(a00, v0[dw],     wa);
        fma8(a10, v0[dw + 1], wa);
        fma8(a01, v1[dw],     wb);
        fma8(a11, v1[dw + 1], wb);
      }
    }

    float a2 = a2_p[0];
    #pragma unroll
    for (int ti = 0; ti < 2; ++ti) {
      long l = l0 + ti;
      const float* pc0 = ti ? a10 : a00;
      const float* pc1 = ti ? a11 : a01;
      f16x8 o8;
      if (c0 < 1024) {
        #pragma unroll
        for (int j = 0; j < 8; ++j) o8[j] = (f16)(a2 * fsilu(pc0[j]));
        *(f16x8*)&g2[l * 2048 + 1024 + c0] = o8;
      } else {
        #pragma unroll
        for (int j = 0; j < 8; ++j) o8[j] = (f16)fsilu(pc0[j]);
        *(f16x8*)&xbc[l * (long)CONVD + (c0 - 1024)] = o8;
      }
      f16x8 o9;
      #pragma unroll
      for (int j = 0; j < 8; ++j) o9[j] = (f16)fsilu(pc1[j]);
      *(f16x8*)&xbc[l * (long)CONVD + (c1 - 1024)] = o9;
    }
  } else if (t < 164) {
    int idx = t - 132;
    int ti = idx >> 4;
    int hd = (idx & 15) * 8;
    long l = l0 + ti;
    f16x8 x = *(const f16x8*)&zx[l * (long)DPROJ + NCV + hd];
    f32x4 o0, o1;
    #pragma unroll
    for (int j = 0; j < 8; ++j) {
      float xx = (float)x[j] + dt_bias[hd + j];
      float sp = (xx > 20.f) ? xx : log1pf(__expf(xx));
      float dv = sp * __expf(A_log[hd + j]);
      if (j < 4) o0[j] = dv; else o1[j-4] = dv;
    }
    *(f32x4*)&dAb[l * 128 + hd]     = o0;
    *(f32x4*)&dAb[l * 128 + hd + 4] = o1;
  }
}

// ---------------- KV partials over 32-token slices (vectorized B loads) ----------------
__global__ __launch_bounds__(512) void k_kv_part(const f16* __restrict__ xbc,
                                                 const float* __restrict__ dA,
                                                 float* __restrict__ part) {
  int t = threadIdx.x;
  int m = t >> 3, p = t & 7;
  int lc = blockIdx.x, b = blockIdx.y;
  float acc0[16], acc1[16];
  #pragma unroll
  for (int s = 0; s < 16; ++s) { acc0[s] = 0.f; acc1[s] = 0.f; }
  long lbase = (long)b * LPB + lc * 32;
  #pragma unroll 2
  for (int li = 0; li < 32; ++li) {
    long row = lbase + li;
    const f16* xr = xbc + row * CONVD;
    float2 aa = *(const float2*)&dA[row * 128 + 2*m];
    float xv0 = (float)xr[16*m + p]     * aa.x;
    float xv1 = (float)xr[16*m + 8 + p] * aa.y;
    uint4 q0 = *(const uint4*)(xr + DIN);
    uint4 q1 = *(const uint4*)(xr + DIN + 8);
    uint4 q2 = *(const uint4*)(xr + DIN + 16);
    uint4 q3 = *(const uint4*)(xr + DIN + 24);
    unsigned a0[4] = {q0.x, q0.y, q0.z, q0.w};
    unsigned a1[4] = {q1.x, q1.y, q1.z, q1.w};
    unsigned a2v[4] = {q2.x, q2.y, q2.z, q2.w};
    unsigned a3[4] = {q3.x, q3.y, q3.z, q3.w};
    #pragma unroll
    for (int k = 0; k < 4; ++k) {
      fmixl(acc0[2*k],     a0[k], xv0);  fmixh(acc0[2*k+1],     a0[k], xv0);
      fmixl(acc0[8+2*k],   a1[k], xv0);  fmixh(acc0[8+2*k+1],   a1[k], xv0);
      fmixl(acc1[2*k],     a2v[k], xv1); fmixh(acc1[2*k+1],     a2v[k], xv1);
      fmixl(acc1[8+2*k],   a3[k], xv1);  fmixh(acc1[8+2*k+1],   a3[k], xv1);
    }
  }
  long base = ((long)(b*128 + lc)) * 16384 + (long)m * 256;
  #pragma unroll
  for (int s = 0; s < 16; ++s) {
    part[base + s*8 + p]       = acc0[s];
    part[base + 128 + s*8 + p] = acc1[s];
  }
}

__global__ __launch_bounds__(256) void k_kv_red(const float* __restrict__ part,
                                                float* __restrict__ KV) {
  int e = blockIdx.x * 256 + threadIdx.x;
  int b = blockIdx.y;
  float s = 0.f;
  #pragma unroll 4
  for (int lc = 0; lc < 128; ++lc) s += part[((long)(b*128 + lc)) * 16384 + e];
  KV[(long)b * 16384 + e] = s;
}

// --- y = Q*KV + x*Dp, LayerNorm, scale/shift, *alpha1 -> g2 cols [0,1024) f16 ---
__global__ __launch_bounds__(256) void k_y_ln(const f16* __restrict__ xbc,
                                              const float* __restrict__ KV,
                                              const float* __restrict__ Dp,
                                              const float* __restrict__ ln_g,
                                              const float* __restrict__ ln_b,
                                              const float* __restrict__ sc_p,
                                              const float* __restrict__ sh_p,
                                              const float* __restrict__ a1_p,
                                              f16* __restrict__ g2) {
  __shared__ float Qs[32][32];
  __shared__ float red[2][8];
  int t = threadIdx.x;
  int hd = t >> 1, pb = (t & 1) * 4;
  int m = hd >> 1, g = hd & 1;
  int b = blockIdx.x >> 7;
  long l0 = (long)b * LPB + (blockIdx.x & 127) * 32;

  f32x4 kv[16];
  #pragma unroll
  for (int s = 0; s < 16; ++s)
    kv[s] = *(const f32x4*)&KV[(long)b * 16384 + m*256 + g*128 + s*8 + pb];

  if (t < 128) {
    int tok = t >> 2, q8 = (t & 3) * 8;
    f16x8 qv = *(const f16x8*)&xbc[(l0 + tok) * CONVD + 1056 + q8];
    #pragma unroll
    for (int j = 0; j < 8; ++j) Qs[tok][q8 + j] = (float)qv[j];
  }
  int c0 = hd*8 + pb;
  f32x4 lg = *(const f32x4*)&ln_g[c0];
  f32x4 lb = *(const f32x4*)&ln_b[c0];
  float dpv = Dp[hd];
  float sc = sc_p[0], sh = sh_p[0], a1 = a1_p[0];
  int wv = t >> 6, lane = t & 63;
  __syncthreads();

  for (int tok = 0; tok < 32; ++tok) {
    long row = l0 + tok;
    f16x4 xr4 = *(const f16x4*)&xbc[row * CONVD + c0];
    f32x4 yv;
    #pragma unroll
    for (int j = 0; j < 4; ++j) yv[j] = (float)xr4[j] * dpv;
    #pragma unroll
    for (int s = 0; s < 16; ++s) {
      float qv = Qs[tok][g*16 + s];
      #pragma unroll
      for (int j = 0; j < 4; ++j) yv[j] = fmaf(qv, kv[s][j], yv[j]);
    }
    float s1 = yv[0] + yv[1] + yv[2] + yv[3];
    float s2 = yv[0]*yv[0] + yv[1]*yv[1] + yv[2]*yv[2] + yv[3]*yv[3];
    #pragma unroll
    for (int off = 1; off < 64; off <<= 1) {
      s1 += __shfl_xor(s1, off, 64);
      s2 += __shfl_xor(s2, off, 64);
    }
    if (lane == 0) { red[tok & 1][wv*2] = s1; red[tok & 1][wv*2 + 1] = s2; }
    __syncthreads();
    const float* rr = red[tok & 1];
    float S1 = rr[0] + rr[2] + rr[4] + rr[6];
    float S2 = rr[1] + rr[3] + rr[5] + rr[7];
    float mu   = S1 * (1.f/1024.f);
    float var  = S2 * (1.f/1024.f) - mu*mu;
    float rstd = rsqrtf(var + 1e-5f);
    f16x4 o4;
    #pragma unroll
    for (int j = 0; j < 4; ++j) {
      float yn = (yv[j] - mu) * rstd * lg[j] + lb[j];
      o4[j] = (f16)(a1 * (yn * sc + sh));
    }
    *(f16x4*)&g2[row * 2048 + c0] = o4;
  }
}

// ---------------- host launcher ----------------
extern "C" void kernel_launch(void* const* d_in, const int* in_sizes, int n_in,
                              void* d_out, int out_size, void* d_ws, size_t ws_size,
                              hipStream_t stream) {
  const float* u       = (const float*)d_in[0];
  const float* W_in    = (const float*)d_in[3];
  const float* dt_bias = (const float*)d_in[4];
  const float* A_log   = (const float*)d_in[5];
  const float* Dp      = (const float*)d_in[6];
  const float* w33     = (const float*)d_in[7];
  const float* w13x1   = (const float*)d_in[8];
  const float* w31x1   = (const float*)d_in[9];
  const float* w13x2   = (const float*)d_in[10];
  const float* w31x2   = (const float*)d_in[11];
  const float* w13bc1  = (const float*)d_in[12];
  const float* w31bc1  = (const float*)d_in[13];
  const float* w13bc2  = (const float*)d_in[14];
  const float* w31bc2  = (const float*)d_in[15];
  const float* wz      = (const float*)d_in[16];
  const float* ln_g    = (const float*)d_in[17];
  const float* ln_b    = (const float*)d_in[18];
  const float* sc      = (const float*)d_in[19];
  const float* sh      = (const float*)d_in[20];
  const float* a1      = (const float*)d_in[21];
  const float* a2      = (const float*)d_in[22];
  const float* W_out   = (const float*)d_in[23];

  // per-batch buffer bytes (u_f16 aliases g2; kv + gemm2 partials live in zx)
  const size_t B_G2   = 16777216;   // 4096x2048 f16
  const size_t B_ZX   = 18350080;   // 4096x2240 f16
  const size_t B_XBC  = 8912896;    // 4096x1088 f16
  const size_t B_DA   = 2097152;    // 4096x128 f32
  const size_t B_KV   = 65536;      // 16384 f32
  const size_t perC   = B_G2 + B_ZX + B_XBC + B_DA + B_KV;   // 46.2 MB
  const size_t persist = 2359296 + 2097152 + 38912;

  int C = 8;
  while (C > 1 && persist + (size_t)C * perC > ws_size) C >>= 1;
  const int nch = 8 / C;
  const int Mc  = C * LPB;

  char* p = (char*)d_ws;
  f16*   win_f   = (f16*)p;   p += 2359296;   // 2304x512
  f16*   wout_f  = (f16*)p;   p += 2097152;   // 512x2048
  f16*   keffall = (f16*)p;   p += 38912;     // 9x2112 f16 (padded)
  char*  arena   = p;                          // u_f16 aliases g2 (conv rewrites it later)
  f16*   g2      = (f16*)arena;
  f16*   u_f     = (f16*)arena;
  p = arena + (size_t)C * B_G2;
  f16*   zx      = (f16*)p;   p += (size_t)C * B_ZX;
  f16*   xbc     = (f16*)p;   p += (size_t)C * B_XBC;
  float* dAb     = (float*)p; p += (size_t)C * B_DA;
  float* KV      = (float*)p; p += (size_t)C * B_KV;
  float* part   = (float*)zx;                 // kv partials (after conv, zx dead)
  f16*   kpart  = (f16*)zx;                   // gemm2 split-K f16 partials

  k_cvt_win<<<4608, 256, 0, stream>>>(W_in, win_f);
  k_cvt    <<<1024, 256, 0, stream>>>(W_out, wout_f);   // 512*2048/1024
  k_keff   <<<9, 256, 0, stream>>>(w33, w13x1, w31x1, w13x2, w31x2,
                                   w13bc1, w31bc1, w13bc2, w31bc2, wz, keffall);

  for (int ch = 0; ch < nch; ++ch) {
    const float* uc   = u + (size_t)ch * Mc * 512;
    float*       outc = (float*)d_out + (size_t)ch * Mc * 512;
    const int ntm = Mc / 128;

    k_cvt<<<Mc/2, 256, 0, stream>>>(uc, u_f);   // u -> f16

    // GEMM1: zx(f16) = u_f @ W_in^T  (N padded to 2304, store-guard 2240)
    k_gemmf<f16><<<ntm*18, 256, 0, stream>>>(u_f, 512, win_f, 512,
                                             zx, DPROJ, 512, DPROJ, 18, ntm*18, 0);

    // fused f16 conv (token-pair x dual-chain) + dA
    k_conv_all<<<Mc/2, 192, 0, stream>>>(zx, keffall, a2, dt_bias, A_log,
                                         xbc, g2, dAb);

    // attention KV (zx arena now dead -> partials live there)
    k_kv_part <<<dim3(128, C), 512, 0, stream>>>(xbc, dAb, part);
    k_kv_red  <<<dim3(64, C), 256, 0, stream>>>(part, KV);
    k_y_ln    <<<C*128, 256, 0, stream>>>(xbc, KV, Dp, ln_g, ln_b, sc, sh, a1, g2);

    // GEMM2: 8-phase 256x256 split-K=2 (1 block/CU, NT=16 deep pipeline),
    // f16 partials in zx arena, then reduce into out.
    const int ntm8 = Mc / 256;                 // 64
    const long cseg = (long)Mc * 512;          // f16 elements per partial
    k_gemm8<<<ntm8*2*2, 512, 0, stream>>>(g2, 2048, wout_f, 2048,
                                          kpart, 512, 1024, 512, 2, ntm8*2, cseg);
    k_red2h<<<Mc/2, 256, 0, stream>>>(kpart, cseg, outc);
  }
}